// Round 4
// baseline (166807.349 us; speedup 1.0000x reference)
//
#include <hip/hip_runtime.h>
#include <hip/hip_bf16.h>

// HRM-LM on MI355X — one-sync-per-round redundant-gate design.
// 128 worker WGs (1/CU) + 1 dedicated sync-master WG.
// Per round: owners compute GEMM cols -> push raw pre-activations + stats
// partials to LLC (sc1) -> arrive(epoch) -> master releases -> every WG reads
// the full raw matrix + stats, redundantly computes LN+gates for ALL h into
// its own LDS. h never crosses WGs; only raw activations do. low_Wh resident
// in LDS; xi = XW(x, once/token) + h_h@Wi_h. Logits: deferred bf16 MFMA GEMM.

#define NWG 128
#define NTH 256
#define EPSV 1e-5f
#define NEP 4608   // one sync per round: 256*3*(5+1)

typedef __attribute__((ext_vector_type(4))) float f32x4;
typedef __attribute__((ext_vector_type(8))) short short8;
typedef unsigned long long u64;

struct PArgs {
  const int* ids; const float* emb; const float* lng; const float* lnb;
  const float* lWi; const float* lbi; const float* lWh; const float* lbh;
  const float* llig; const float* llib; const float* llhg; const float* llhb;
  const float* hWi; const float* hbi; const float* hWh; const float* hbh;
  const float* hlig; const float* hlib; const float* hlhg; const float* hlhb;
  int* arr; int* rel; u64* statsG; float* stgG;
  __hip_bfloat16* hist; float* WiT; float* hWiT; float* hWhT;
};

__device__ __forceinline__ float sigm(float x) { return 1.f / (1.f + __expf(-x)); }
__device__ __forceinline__ float tanh_f(float x) {
  x = fminf(15.f, fmaxf(-15.f, x));
  float e = __expf(2.f * x);
  return (e - 1.f) / (e + 1.f);
}
__device__ __forceinline__ int aldi(const int* p) {
  return __hip_atomic_load(p, __ATOMIC_RELAXED, __HIP_MEMORY_SCOPE_AGENT);
}
__device__ __forceinline__ u64 aldu(const u64* p) {
  return __hip_atomic_load(p, __ATOMIC_RELAXED, __HIP_MEMORY_SCOPE_AGENT);
}
__device__ __forceinline__ float2 ald2(const float* p) {
  union { u64 u; float2 f; } c;
  c.u = __hip_atomic_load((const u64*)p, __ATOMIC_RELAXED, __HIP_MEMORY_SCOPE_AGENT);
  return c.f;
}
__device__ __forceinline__ void astu(u64* p, u64 v) {
  __hip_atomic_store(p, v, __ATOMIC_RELAXED, __HIP_MEMORY_SCOPE_AGENT);
}
__device__ __forceinline__ void asti(int* p, int v) {
  __hip_atomic_store(p, v, __ATOMIC_RELAXED, __HIP_MEMORY_SCOPE_AGENT);
}

__global__ void __launch_bounds__(NTH) hrm_recur(PArgs P) {
  // ---------------- dedicated sync master (block NWG) ----------------
  if (blockIdx.x == NWG) {
    if (threadIdx.x < 64) {
      const u64* ap = (const u64*)P.arr + threadIdx.x;
      for (int ep = 1; ep <= NEP; ++ep) {
        int lim = 1 << 22;
        bool good = true;
        for (;;) {
          u64 v = aldu(ap);
          int a0 = (int)(unsigned)(v & 0xffffffffull);
          int a1 = (int)(unsigned)(v >> 32);
          if (__all(a0 >= ep && a1 >= ep)) break;
          if (--lim == 0) { good = false; break; }
          __builtin_amdgcn_s_sleep(1);
        }
        int pub = good ? ep : (1 << 30);
        if (threadIdx.x < 8) asti(P.rel + threadIdx.x * 16, pub);
        if (!good) return;
      }
    }
    return;
  }

  // ---------------- worker ----------------
  __shared__ float WhS[24 * 1024];   // low_Wh slice [c][k]
  __shared__ float hL[8 * 1024];     // h_l, redundant local copy
  __shared__ float hH[8 * 768];      // h_h, redundant local copy
  __shared__ float XW[24 * 8];       // x @ Wi_x for own 24 cols (per token)
  __shared__ float stg[2][24 * 8];   // raw (bias-added) GEMM outputs (own cols)
  __shared__ float sred[96];         // (m, rs) per (set,g,b)
  __shared__ float xm[8], xrs[8];
  __shared__ int idsh[8];
  __shared__ int okf;

  const int wg = blockIdx.x, tid = threadIdx.x;
  const int ks = tid & 31, cg = tid >> 5;
  const int lj8 = wg * 8, lj6 = wg * 6;

  int epoch = 0;
  auto arrive_wait = [&]() -> bool {
    ++epoch;
    asm volatile("s_waitcnt vmcnt(0)" ::: "memory");
    __syncthreads();
    if (tid == 0) {
      asti(P.arr + wg, epoch);
      const int* rp = P.rel + (wg & 7) * 16;
      int lim = 1 << 21, v = 0;
      do {
        v = aldi(rp);
        if (v >= epoch) break;
        __builtin_amdgcn_s_sleep(2);
      } while (--lim);
      okf = (lim != 0 && v < (1 << 29)) ? 1 : 0;
    }
    __syncthreads();
    return okf != 0;
  };

  // ---- GEMMs: thread (cg,ks) owns 3 cols, k-chunks k = i*128 + ks*4 ----
  auto gemm_lowh = [&](float (&acc)[3][8]) {
    const int c0 = cg * 3;
    const float* w0p = &WhS[(c0 + 0) * 1024];
    const float* w1p = &WhS[(c0 + 1) * 1024];
    const float* w2p = &WhS[(c0 + 2) * 1024];
    #pragma unroll
    for (int i = 0; i < 8; ++i) {
      int k = i * 128 + ks * 4;
      float4 w0 = *(const float4*)&w0p[k];
      float4 w1 = *(const float4*)&w1p[k];
      float4 w2 = *(const float4*)&w2p[k];
      #pragma unroll
      for (int b = 0; b < 8; ++b) {
        float4 h = *(const float4*)&hL[b * 1024 + k];
        acc[0][b] += w0.x*h.x + w0.y*h.y + w0.z*h.z + w0.w*h.w;
        acc[1][b] += w1.x*h.x + w1.y*h.y + w1.z*h.z + w1.w*h.w;
        acc[2][b] += w2.x*h.x + w2.y*h.y + w2.z*h.z + w2.w*h.w;
      }
    }
  };
  auto gemm_xih = [&](float (&acc)[3][8]) {   // h_h part of xi: K=768
    const float* wp[3];
    #pragma unroll
    for (int cc = 0; cc < 3; ++cc) {
      int c = cg * 3 + cc; int g = c >> 3, jj = c & 7;
      wp[cc] = P.WiT + ((size_t)g * 1024 + lj8 + jj) * 1536 + 768;
    }
    #pragma unroll
    for (int i = 0; i < 6; ++i) {
      int k = i * 128 + ks * 4;
      float4 w0 = *(const float4*)&wp[0][k];
      float4 w1 = *(const float4*)&wp[1][k];
      float4 w2 = *(const float4*)&wp[2][k];
      #pragma unroll
      for (int b = 0; b < 8; ++b) {
        float4 h = *(const float4*)&hH[b * 768 + k];
        acc[0][b] += w0.x*h.x + w0.y*h.y + w0.z*h.z + w0.w*h.w;
        acc[1][b] += w1.x*h.x + w1.y*h.y + w1.z*h.z + w1.w*h.w;
        acc[2][b] += w2.x*h.x + w2.y*h.y + w2.z*h.z + w2.w*h.w;
      }
    }
  };
  auto gemm_hxi = [&](float (&acc)[3][8]) {  // K=1024 over hL, 18 cols
    if (cg >= 6) return;
    const float* wp[3];
    #pragma unroll
    for (int cc = 0; cc < 3; ++cc) {
      int c = cg * 3 + cc; int g = c / 6, jj = c % 6;
      wp[cc] = P.hWiT + ((size_t)g * 768 + lj6 + jj) * 1024;
    }
    #pragma unroll
    for (int i = 0; i < 8; ++i) {
      int k = i * 128 + ks * 4;
      float4 w0 = *(const float4*)&wp[0][k];
      float4 w1 = *(const float4*)&wp[1][k];
      float4 w2 = *(const float4*)&wp[2][k];
      #pragma unroll
      for (int b = 0; b < 8; ++b) {
        float4 h = *(const float4*)&hL[b * 1024 + k];
        acc[0][b] += w0.x*h.x + w0.y*h.y + w0.z*h.z + w0.w*h.w;
        acc[1][b] += w1.x*h.x + w1.y*h.y + w1.z*h.z + w1.w*h.w;
        acc[2][b] += w2.x*h.x + w2.y*h.y + w2.z*h.z + w2.w*h.w;
      }
    }
  };
  auto gemm_hhh = [&](float (&acc)[3][8]) {  // K=768 over hH, 18 cols
    if (cg >= 6) return;
    const float* wp[3];
    #pragma unroll
    for (int cc = 0; cc < 3; ++cc) {
      int c = cg * 3 + cc; int g = c / 6, jj = c % 6;
      wp[cc] = P.hWhT + ((size_t)g * 768 + lj6 + jj) * 768;
    }
    #pragma unroll
    for (int i = 0; i < 6; ++i) {
      int k = i * 128 + ks * 4;
      float4 w0 = *(const float4*)&wp[0][k];
      float4 w1 = *(const float4*)&wp[1][k];
      float4 w2 = *(const float4*)&wp[2][k];
      #pragma unroll
      for (int b = 0; b < 8; ++b) {
        float4 h = *(const float4*)&hH[b * 768 + k];
        acc[0][b] += w0.x*h.x + w0.y*h.y + w0.z*h.z + w0.w*h.w;
        acc[1][b] += w1.x*h.x + w1.y*h.y + w1.z*h.z + w1.w*h.w;
        acc[2][b] += w2.x*h.x + w2.y*h.y + w2.z*h.z + w2.w*h.w;
      }
    }
  };

  auto redstage = [&](float (&acc)[3][8], int set, const float* bias, int dim,
                      int perg, int jb, bool addXW) {
    #pragma unroll
    for (int cc = 0; cc < 3; ++cc)
      #pragma unroll
      for (int b = 0; b < 8; ++b) {
        float v = acc[cc][b];
        #pragma unroll
        for (int m = 1; m < 32; m <<= 1) v += __shfl_xor(v, m, 64);
        acc[cc][b] = v;
      }
    if ((tid & 31) == 0) {
      int cgl = tid >> 5;
      #pragma unroll
      for (int cc = 0; cc < 3; ++cc) {
        int c = cgl * 3 + cc;
        if (c < perg * 3) {
          int g = (perg == 8) ? (c >> 3) : (c / 6);
          int jj = (perg == 8) ? (c & 7) : (c % 6);
          float bs = bias[g * dim + jb + jj];
          #pragma unroll
          for (int b = 0; b < 8; ++b) {
            float v = acc[cc][b] + bs;
            if (addXW) v += XW[c * 8 + b];
            stg[set][c * 8 + b] = v;
          }
        }
      }
    }
  };

  // per-WG (s1,s2) partial -> private u64 slot in statsG[e][row][wg]
  auto stats_put = [&](int e, int set, int perg) {
    if (tid < 24) {
      int g = tid >> 3, b = tid & 7;
      float s1 = 0.f, s2 = 0.f;
      for (int jj = 0; jj < perg; ++jj) {
        float v = stg[set][(g * perg + jj) * 8 + b];
        s1 += v; s2 += v * v;
      }
      union { u64 u; float f[2]; } c; c.f[0] = s1; c.f[1] = s2;
      astu(P.statsG + ((size_t)e * 48 + set * 24 + tid) * 128 + wg, c.u);
    }
  };
  // reduce 128 partials per row; rows<24 from e0 (set0), rows>=24 from e1
  auto stats_read = [&](int e0, int e1, float invD) {
    if (tid < 48) {
      int set = tid / 24;
      int e = set ? e1 : e0;
      const u64* b0 = P.statsG + ((size_t)e * 48 + tid) * 128;
      float s1 = 0.f, s2 = 0.f;
      #pragma unroll 8
      for (int w = 0; w < 128; ++w) {
        union { u64 u; float f[2]; } c; c.u = aldu(b0 + w);
        s1 += c.f[0]; s2 += c.f[1];
      }
      int pp = tid % 24, g = pp >> 3, b = pp & 7;
      float m = s1 * invD;
      float rs = rsqrtf(s2 * invD - m * m + EPSV);
      sred[set * 48 + g * 16 + b * 2] = m;
      sred[set * 48 + g * 16 + b * 2 + 1] = rs;
    }
    __syncthreads();
  };

  // push own raw cols: stgG layout [e][set][g][j(1024)][b(8)]
  auto push_low = [&](int e, int set) {
    if (tid < 96) {
      int g = tid >> 5, idx = tid & 31;
      u64 v = *(const u64*)&stg[set][g * 64 + idx * 2];
      float* gb = P.stgG + ((size_t)(e * 2 + set)) * 24576 + g * 8192 + lj8 * 8 + idx * 2;
      astu((u64*)gb, v);
    }
  };
  auto push_high = [&](int e, int set) {
    if (tid < 72) {
      int g = tid / 24, idx = tid % 24;
      u64 v = *(const u64*)&stg[set][g * 48 + idx * 2];
      float* gb = P.stgG + ((size_t)(e * 2 + set)) * 24576 + g * 8192 + lj6 * 8 + idx * 2;
      astu((u64*)gb, v);
    }
  };

  // redundant gate: every WG computes ALL of h_l from the raw matrix
  auto gate_low = [&](int e0, int e1) {
    const float* S0 = P.stgG + (size_t)(e0 * 2 + 0) * 24576;
    const float* S1 = P.stgG + (size_t)(e1 * 2 + 1) * 24576;
    #pragma unroll
    for (int half = 0; half < 2; ++half) {
      int j0 = tid * 4 + half * 2;
      float A0[3][16], A1[3][16];
      #pragma unroll
      for (int g = 0; g < 3; ++g) {
        const float* p0 = S0 + g * 8192 + j0 * 8;
        const float* p1 = S1 + g * 8192 + j0 * 8;
        #pragma unroll
        for (int q = 0; q < 8; ++q) {
          float2 v0 = ald2(p0 + q * 2); A0[g][q*2] = v0.x; A0[g][q*2+1] = v0.y;
          float2 v1 = ald2(p1 + q * 2); A1[g][q*2] = v1.x; A1[g][q*2+1] = v1.y;
        }
      }
      #pragma unroll
      for (int jj = 0; jj < 2; ++jj) {
        int j = j0 + jj;
        float gx[3], bx[3], gh[3], bh[3];
        #pragma unroll
        for (int g = 0; g < 3; ++g) {
          gx[g] = P.llig[g * 1024 + j]; bx[g] = P.llib[g * 1024 + j];
          gh[g] = P.llhg[g * 1024 + j]; bh[g] = P.llhb[g * 1024 + j];
        }
        #pragma unroll
        for (int b = 0; b < 8; ++b) {
          float xin[3], hin[3];
          #pragma unroll
          for (int g = 0; g < 3; ++g) {
            float m = sred[g * 16 + b * 2], rs = sred[g * 16 + b * 2 + 1];
            xin[g] = (A0[g][jj * 8 + b] - m) * rs * gx[g] + bx[g];
            float m2 = sred[48 + g * 16 + b * 2], rs2 = sred[48 + g * 16 + b * 2 + 1];
            hin[g] = (A1[g][jj * 8 + b] - m2) * rs2 * gh[g] + bh[g];
          }
          float rg = sigm(xin[0] + hin[0]);
          float zg = sigm(xin[1] + hin[1]);
          float ng = tanh_f(xin[2] + rg * hin[2]);
          float ho = hL[b * 1024 + j];
          hL[b * 1024 + j] = (1.f - zg) * ng + zg * ho;
        }
      }
    }
  };

  auto gate_high = [&](int e) {
    const float* S0 = P.stgG + (size_t)(e * 2 + 0) * 24576;
    const float* S1 = P.stgG + (size_t)(e * 2 + 1) * 24576;
    #pragma unroll
    for (int jj = 0; jj < 3; ++jj) {
      int j = tid * 3 + jj;
      float A0[3][8], A1[3][8];
      #pragma unroll
      for (int g = 0; g < 3; ++g) {
        const float* p0 = S0 + g * 8192 + j * 8;
        const float* p1 = S1 + g * 8192 + j * 8;
        #pragma unroll
        for (int q = 0; q < 4; ++q) {
          float2 v0 = ald2(p0 + q * 2); A0[g][q*2] = v0.x; A0[g][q*2+1] = v0.y;
          float2 v1 = ald2(p1 + q * 2); A1[g][q*2] = v1.x; A1[g][q*2+1] = v1.y;
        }
      }
      float gx[3], bx[3], gh[3], bh[3];
      #pragma unroll
      for (int g = 0; g < 3; ++g) {
        gx[g] = P.hlig[g * 768 + j]; bx[g] = P.hlib[g * 768 + j];
        gh[g] = P.hlhg[g * 768 + j]; bh[g] = P.hlhb[g * 768 + j];
      }
      #pragma unroll
      for (int b = 0; b < 8; ++b) {
        float xin[3], hin[3];
        #pragma unroll
        for (int g = 0; g < 3; ++g) {
          float m = sred[g * 16 + b * 2], rs = sred[g * 16 + b * 2 + 1];
          xin[g] = (A0[g][b] - m) * rs * gx[g] + bx[g];
          float m2 = sred[48 + g * 16 + b * 2], rs2 = sred[48 + g * 16 + b * 2 + 1];
          hin[g] = (A1[g][b] - m2) * rs2 * gh[g] + bh[g];
        }
        float rg = sigm(xin[0] + hin[0]);
        float zg = sigm(xin[1] + hin[1]);
        float ng = tanh_f(xin[2] + rg * hin[2]);
        float ho = hH[b * 768 + j];
        hH[b * 768 + j] = (1.f - zg) * ng + zg * ho;
      }
    }
  };

  // per token: LN stats of x + XW = x @ Wi_x  (all local, redundant)
  auto xfun = [&](int tt) {
    int b = tid >> 5, u = tid & 31;
    if (tid < 8) idsh[tid] = P.ids[tid * 256 + tt];
    int id = P.ids[b * 256 + tt];
    const float* e = P.emb + (size_t)id * 768;
    float s1 = 0.f, s2 = 0.f;
    #pragma unroll
    for (int q = 0; q < 24; q += 4) {
      float4 v = *(const float4*)&e[u * 24 + q];
      s1 += v.x + v.y + v.z + v.w;
      s2 += v.x*v.x + v.y*v.y + v.z*v.z + v.w*v.w;
    }
    #pragma unroll
    for (int m = 1; m < 32; m <<= 1) { s1 += __shfl_xor(s1, m, 64); s2 += __shfl_xor(s2, m, 64); }
    if (u == 0) { float mm = s1 / 768.f; xm[b] = mm; xrs[b] = rsqrtf(s2 / 768.f - mm * mm + EPSV); }
    __syncthreads();
    // XW GEMM over k in [0,768)
    float acc[3][8] = {};
    const float* wp[3];
    #pragma unroll
    for (int cc = 0; cc < 3; ++cc) {
      int c = cg * 3 + cc; int g = c >> 3, jj = c & 7;
      wp[cc] = P.WiT + ((size_t)g * 1024 + lj8 + jj) * 1536;
    }
    int idv[8];
    #pragma unroll
    for (int bb = 0; bb < 8; ++bb) idv[bb] = idsh[bb];
    #pragma unroll
    for (int i = 0; i < 6; ++i) {
      int k = i * 128 + ks * 4;
      float4 w0 = *(const float4*)&wp[0][k];
      float4 w1 = *(const float4*)&wp[1][k];
      float4 w2 = *(const float4*)&wp[2][k];
      float4 gam = *(const float4*)&P.lng[k];
      float4 bet = *(const float4*)&P.lnb[k];
      #pragma unroll
      for (int bb = 0; bb < 8; ++bb) {
        float4 xv = *(const float4*)&P.emb[(size_t)idv[bb] * 768 + k];
        float4 xn;
        xn.x = (xv.x - xm[bb]) * xrs[bb] * gam.x + bet.x;
        xn.y = (xv.y - xm[bb]) * xrs[bb] * gam.y + bet.y;
        xn.z = (xv.z - xm[bb]) * xrs[bb] * gam.z + bet.z;
        xn.w = (xv.w - xm[bb]) * xrs[bb] * gam.w + bet.w;
        acc[0][bb] += w0.x*xn.x + w0.y*xn.y + w0.z*xn.z + w0.w*xn.w;
        acc[1][bb] += w1.x*xn.x + w1.y*xn.y + w1.z*xn.z + w1.w*xn.w;
        acc[2][bb] += w2.x*xn.x + w2.y*xn.y + w2.z*xn.z + w2.w*xn.w;
      }
    }
    #pragma unroll
    for (int cc = 0; cc < 3; ++cc)
      #pragma unroll
      for (int bb = 0; bb < 8; ++bb) {
        float v = acc[cc][bb];
        #pragma unroll
        for (int m = 1; m < 32; m <<= 1) v += __shfl_xor(v, m, 64);
        acc[cc][bb] = v;
      }
    if ((tid & 31) == 0) {
      int cgl = tid >> 5;
      #pragma unroll
      for (int cc = 0; cc < 3; ++cc)
        #pragma unroll
        for (int bb = 0; bb < 8; ++bb)
          XW[(cgl * 3 + cc) * 8 + bb] = acc[cc][bb];
    }
    __syncthreads();
  };

  // =================== prologue ===================
  for (int i = tid; i < 8 * 1024; i += NTH) hL[i] = 0.f;
  for (int i = tid; i < 8 * 768; i += NTH) hH[i] = 0.f;
  #pragma unroll 1
  for (int g = 0; g < 3; ++g)
    for (int it = 0; it < 6; ++it) {   // low_Wi [3][1536][1024] -> WiT[g][j][k]
      int k = it * 256 + tid;
      const float* src = P.lWi + ((size_t)g * 1536 + k) * 1024 + lj8;
      float4 v0 = *(const float4*)src; float4 v1 = *(const float4*)(src + 4);
      float vv[8] = {v0.x, v0.y, v0.z, v0.w, v1.x, v1.y, v1.z, v1.w};
      for (int jj = 0; jj < 8; ++jj)
        P.WiT[((size_t)g * 1024 + lj8 + jj) * 1536 + k] = vv[jj];
    }
  #pragma unroll 1
  for (int g = 0; g < 3; ++g)
    for (int it = 0; it < 4; ++it) {   // high_Wi [3][1024][768] -> hWiT[g][j][k]
      int k = it * 256 + tid;
      const float* src = P.hWi + ((size_t)g * 1024 + k) * 768 + lj6;
      float2 a = *(const float2*)src, b2v = *(const float2*)(src + 2), c2v = *(const float2*)(src + 4);
      float vv[6] = {a.x, a.y, b2v.x, b2v.y, c2v.x, c2v.y};
      for (int jj = 0; jj < 6; ++jj)
        P.hWiT[((size_t)g * 768 + lj6 + jj) * 1024 + k] = vv[jj];
    }
  #pragma unroll 1
  for (int g = 0; g < 3; ++g)
    for (int it = 0; it < 3; ++it) {   // high_Wh [3][768][768] -> hWhT[g][j][k]
      int k = it * 256 + tid;
      const float* src = P.hWh + ((size_t)g * 768 + k) * 768 + lj6;
      float2 a = *(const float2*)src, b2v = *(const float2*)(src + 2), c2v = *(const float2*)(src + 4);
      float vv[6] = {a.x, a.y, b2v.x, b2v.y, c2v.x, c2v.y};
      for (int jj = 0; jj < 6; ++jj)
        P.hWhT[((size_t)g * 768 + lj6 + jj) * 768 + k] = vv[jj];
    }
  #pragma unroll 1
  for (int g = 0; g < 3; ++g)
    for (int it = 0; it < 4; ++it) {   // low_Wh slice -> LDS
      int k = it * 256 + tid;
      const float* src = P.lWh + ((size_t)g * 1024 + k) * 1024 + lj8;
      float4 v0 = *(const float4*)src; float4 v1 = *(const float4*)(src + 4);
      float vv[8] = {v0.x, v0.y, v0.z, v0.w, v1.x, v1.y, v1.z, v1.w};
      for (int jj = 0; jj < 8; ++jj) WhS[(g * 8 + jj) * 1024 + k] = vv[jj];
    }
  __syncthreads();
  xfun(0);

  // =================== main recurrence ===================
  int r = 0;
  bool alive = true;
  #pragma unroll 1
  for (int t = 0; alive && t < 256; ++t) {
    #pragma unroll 1
    for (int nn = 0; nn < 3 && alive; ++nn) {
      // ---- round A ----
      ++r; int eA = r & 1;
      {
        float accX[3][8] = {}; float accH[3][8] = {};
        gemm_xih(accX);
        gemm_lowh(accH);
        redstage(accX, 0, P.lbi, 1024, 8, lj8, true);
        redstage(accH, 1, P.lbh, 1024, 8, lj8, false);
        __syncthreads();
        stats_put(eA, 0, 8); stats_put(eA, 1, 8);
        push_low(eA, 0); push_low(eA, 1);
        alive = arrive_wait(); if (!alive) break;
        stats_read(eA, eA, 1.f / 1024.f);
        gate_low(eA, eA);
        __syncthreads();
      }
      // ---- inner iterations 2..5 ----
      #pragma unroll 1
      for (int it = 1; it < 5 && alive; ++it) {
        ++r; int e = r & 1;
        float acc2[3][8] = {};
        gemm_lowh(acc2);
        redstage(acc2, 1, P.lbh, 1024, 8, lj8, false);
        __syncthreads();
        stats_put(e, 1, 8);
        push_low(e, 1);
        alive = arrive_wait(); if (!alive) break;
        stats_read(eA, e, 1.f / 1024.f);
        gate_low(eA, e);
        __syncthreads();
      }
      if (!alive) break;
      // ---- high GRU round ----
      ++r; int eh = r & 1;
      {
        float aX[3][8] = {}; float aH[3][8] = {};
        gemm_hxi(aX);
        gemm_hhh(aH);
        redstage(aX, 0, P.hbi, 768, 6, lj6, false);
        redstage(aH, 1, P.hbh, 768, 6, lj6, false);
        __syncthreads();
        stats_put(eh, 0, 6); stats_put(eh, 1, 6);
        push_high(eh, 0); push_high(eh, 1);
        alive = arrive_wait(); if (!alive) break;
        stats_read(eh, eh, 1.f / 768.f);
        gate_high(eh);
        __syncthreads();
        if (nn == 2) {
          if (tid < 48) {
            int jj = tid % 6, b = tid / 6; int j = lj6 + jj;
            P.hist[((size_t)t * 8 + b) * 768 + j] = __float2bfloat16(hH[b * 768 + j]);
          }
          if (t < 255) { __syncthreads(); xfun(t + 1); }
        }
      }
    }
  }
}

// =================== Wout transpose + bf16 convert ===================
__global__ void __launch_bounds__(256) wout_t(const float* __restrict__ W,
                                              __hip_bfloat16* __restrict__ WT) {
  __shared__ float T[64][65];
  int n0 = blockIdx.x * 64, k0 = blockIdx.y * 64;
  int tid = threadIdx.x;
  int lane16 = tid & 15, grp = tid >> 4;
  #pragma unroll
  for (int i = 0; i < 4; ++i) {
    int kl = i * 16 + grp; int nl = lane16 * 4;
    float4 v = *(const float4*)&W[(size_t)(k0 + kl) * 32000 + n0 + nl];
    T[kl][nl] = v.x; T[kl][nl + 1] = v.y; T[kl][nl + 2] = v.z; T[kl][nl + 3] = v.w;
  }
  __syncthreads();
  #pragma unroll
  for (int i = 0; i < 4; ++i) {
    int nl = i * 16 + grp; int kl = lane16 * 4;
    union { ushort4 v; __hip_bfloat16 h[4]; } u;
    for (int q = 0; q < 4; ++q) u.h[q] = __float2bfloat16(T[kl + q][nl]);
    *(ushort4*)&WT[(size_t)(n0 + nl) * 768 + k0 + kl] = u.v;
  }
}

// =================== logits GEMM: [2048,768] x [768,32000]^T-stored ===================
__global__ void __launch_bounds__(256) logits_gemm(const __hip_bfloat16* __restrict__ Ah,
                                                   const __hip_bfloat16* __restrict__ Bt,
                                                   const float* __restrict__ bias,
                                                   float* __restrict__ out) {
  __shared__ short As[128 * 64];
  __shared__ short Bs[128 * 64];
  int m0 = blockIdx.y * 128, n0 = blockIdx.x * 128;
  int tid = threadIdx.x, lane = tid & 63, w = tid >> 6;
  int wr = w >> 1, wc = w & 1;
  int r16 = lane & 15, khalf = (lane >> 4) * 8;
  f32x4 acc[4][4];
  #pragma unroll
  for (int i = 0; i < 4; ++i)
    #pragma unroll
    for (int j = 0; j < 4; ++j)
      #pragma unroll
      for (int q = 0; q < 4; ++q) acc[i][j][q] = 0.f;

  for (int kt = 0; kt < 12; ++kt) {
    int k0 = kt * 64;
    __syncthreads();
    #pragma unroll
    for (int it = 0; it < 4; ++it) {
      int f = it * 2048 + tid * 8; int row = f >> 6, col = f & 63;
      *(uint4*)&As[f] = *(const uint4*)&Ah[(size_t)(m0 + row) * 768 + k0 + col];
      *(uint4*)&Bs[f] = *(const uint4*)&Bt[(size_t)(n0 + row) * 768 + k0 + col];
    }
    __syncthreads();
    #pragma unroll
    for (int kk = 0; kk < 64; kk += 32) {
      short8 af[4], bfr[4];
      #pragma unroll
      for (int i = 0; i < 4; ++i)
        af[i] = *(short8*)&As[(wr * 64 + i * 16 + r16) * 64 + kk + khalf];
      #pragma unroll
      for (int j = 0; j < 4; ++j)
        bfr[j] = *(short8*)&Bs[(wc * 64 + j * 16 + r16) * 64 + kk + khalf];
      #pragma unroll
      for (int i = 0; i < 4; ++i)
        #pragma unroll
        for (int j = 0; j < 4; ++j)
          acc[i][j] = __builtin_amdgcn_mfma_f32_16x16x32_bf16(af[i], bfr[j], acc[i][j], 0, 0, 0);
    }
  }
  #pragma unroll
  for (int i = 0; i < 4; ++i)
    #pragma unroll
    for (int j = 0; j < 4; ++j)
      #pragma unroll
      for (int q = 0; q < 4; ++q) {
        int m = m0 + wr * 64 + i * 16 + ((lane >> 4) * 4 + q);
        int n = n0 + wc * 64 + j * 16 + (lane & 15);
        out[(size_t)(m & 7) * 8192000 + (size_t)(m >> 3) * 32000 + n] =
            acc[i][j][q] + bias[n];
      }
}

extern "C" void kernel_launch(void* const* d_in, const int* in_sizes, int n_in,
                              void* d_out, int out_size, void* d_ws, size_t ws_size,
                              hipStream_t stream) {
  (void)in_sizes; (void)n_in; (void)out_size; (void)ws_size;
  char* wsb = (char*)d_ws;
  size_t off = 0;
  auto take = [&](size_t bytes) -> void* {
    void* p = wsb + off;
    off += (bytes + 1023) & ~(size_t)1023;
    return p;
  };
  int* arr      = (int*)take((size_t)128 * 4);            // worker epoch slots
  int* rel      = (int*)take((size_t)8 * 16 * 4);         // release broadcast lines
  size_t state_bytes = off;                               // 2 KB -> memset
  u64* statsG   = (u64*)take((size_t)2 * 48 * 128 * 8);   // per-WG stats partials
  float* stgG   = (float*)take((size_t)2 * 2 * 24576 * 4);// raw activations ring
  __hip_bfloat16* hist = (__hip_bfloat16*)take((size_t)2048 * 768 * 2);
  float* WiT    = (float*)take((size_t)3 * 1024 * 1536 * 4);
  float* hWiT   = (float*)take((size_t)3 * 768 * 1024 * 4);
  float* hWhT   = (float*)take((size_t)3 * 768 * 768 * 4);
  __hip_bfloat16* WoutT = (__hip_bfloat16*)take((size_t)32000 * 768 * 2);

  hipMemsetAsync(d_ws, 0, state_bytes, stream);  // arr/rel = 0, epochs start at 1

  wout_t<<<dim3(500, 12), 256, 0, stream>>>((const float*)d_in[20], WoutT);

  PArgs A;
  A.ids = (const int*)d_in[0];   A.emb = (const float*)d_in[1];
  A.lng = (const float*)d_in[2]; A.lnb = (const float*)d_in[3];
  A.lWi = (const float*)d_in[4]; A.lbi = (const float*)d_in[5];
  A.lWh = (const float*)d_in[6]; A.lbh = (const float*)d_in[7];
  A.llig = (const float*)d_in[8];  A.llib = (const float*)d_in[9];
  A.llhg = (const float*)d_in[10]; A.llhb = (const float*)d_in[11];
  A.hWi = (const float*)d_in[12];  A.hbi = (const float*)d_in[13];
  A.hWh = (const float*)d_in[14];  A.hbh = (const float*)d_in[15];
  A.hlig = (const float*)d_in[16]; A.hlib = (const float*)d_in[17];
  A.hlhg = (const float*)d_in[18]; A.hlhb = (const float*)d_in[19];
  A.arr = arr; A.rel = rel; A.statsG = statsG; A.stgG = stgG;
  A.hist = hist; A.WiT = WiT; A.hWiT = hWiT; A.hWhT = hWhT;

  hrm_recur<<<NWG + 1, NTH, 0, stream>>>(A);

  logits_gemm<<<dim3(250, 16), 256, 0, stream>>>(hist, WoutT,
                                                 (const float*)d_in[21],
                                                 (float*)d_out);
}

// Round 5
// 81396.918 us; speedup vs baseline: 2.0493x; 2.0493x over previous
//
#include <hip/hip_runtime.h>
#include <hip/hip_bf16.h>

// HRM-LM on MI355X — owner-gating + master-release sync.
// 128 worker WGs (1/CU) + 1 dedicated master WG.
// Workers: low_Wh resident in LDS; per round compute own 24/18 gate-cols,
// write private (s1,s2) stats partials (plain sc1 stores, no atomics),
// arrive via private epoch slot. Master: polls 128 slots (sole poller),
// reduces stats partials -> (mean, rsqrt), publishes 48 u64 + release.
// Workers gate their own columns, store h slices (sc1), arrive, master
// releases. xi = XW (x@Wi_x once per token, local) + h_h@Wi_h.
// h_h history logged bf16; logits via deferred bf16 MFMA GEMM.

#define NWG 128
#define NTH 256
#define EPSV 1e-5f

typedef __attribute__((ext_vector_type(4))) float f32x4;
typedef __attribute__((ext_vector_type(8))) short short8;
typedef unsigned long long u64;

struct PArgs {
  const int* ids; const float* emb; const float* lng; const float* lnb;
  const float* lWi; const float* lbi; const float* lWh; const float* lbh;
  const float* llig; const float* llib; const float* llhg; const float* llhb;
  const float* hWi; const float* hbi; const float* hWh; const float* hbh;
  const float* hlig; const float* hlib; const float* hlhg; const float* hlhb;
  int* arr; int* rel; u64* statsG; u64* sredG; float* hl; float* hh;
  __hip_bfloat16* hist; float* WiT; float* hWiT; float* hWhT;
};

__device__ __forceinline__ float sigm(float x) { return 1.f / (1.f + __expf(-x)); }
__device__ __forceinline__ float tanh_f(float x) {
  x = fminf(15.f, fmaxf(-15.f, x));
  float e = __expf(2.f * x);
  return (e - 1.f) / (e + 1.f);
}
// agent-scope (device-coherent, sc1) loads/stores: bypass non-coherent L2.
__device__ __forceinline__ void ast(float* p, float v) {
  __hip_atomic_store(p, v, __ATOMIC_RELAXED, __HIP_MEMORY_SCOPE_AGENT);
}
__device__ __forceinline__ int aldi(const int* p) {
  return __hip_atomic_load(p, __ATOMIC_RELAXED, __HIP_MEMORY_SCOPE_AGENT);
}
__device__ __forceinline__ u64 aldu(const u64* p) {
  return __hip_atomic_load(p, __ATOMIC_RELAXED, __HIP_MEMORY_SCOPE_AGENT);
}
__device__ __forceinline__ float2 ald2(const float* p) {
  union { u64 u; float2 f; } c;
  c.u = __hip_atomic_load((const u64*)p, __ATOMIC_RELAXED, __HIP_MEMORY_SCOPE_AGENT);
  return c.f;
}
__device__ __forceinline__ void astu(u64* p, u64 v) {
  __hip_atomic_store(p, v, __ATOMIC_RELAXED, __HIP_MEMORY_SCOPE_AGENT);
}
__device__ __forceinline__ void asti(int* p, int v) {
  __hip_atomic_store(p, v, __ATOMIC_RELAXED, __HIP_MEMORY_SCOPE_AGENT);
}

__global__ void __launch_bounds__(NTH) hrm_recur(PArgs P) {
  const int tid = threadIdx.x;

  // ================= dedicated sync/reduce master =================
  if (blockIdx.x == NWG) {
    __shared__ float mbuf[192][2];
    __shared__ int mok;
    // event: wait all arr>=e; if n>0 reduce stats rows [lo,lo+n) of parity par
    auto mevent = [&](int e, int lo, int n, float invD, int par) -> bool {
      if (tid < 64) {
        const u64* ap = (const u64*)P.arr + tid;
        int lim = 1 << 22, good = 1;
        for (;;) {
          u64 v = aldu(ap);
          int a0 = (int)(unsigned)(v & 0xffffffffull);
          int a1 = (int)(unsigned)(v >> 32);
          if (__all(a0 >= e && a1 >= e)) break;
          if (--lim == 0) { good = 0; break; }
          __builtin_amdgcn_s_sleep(1);
        }
        if (tid == 0) mok = good;
      }
      __syncthreads();
      bool good = (mok != 0);
      if (good && n > 0) {
        if (tid < n * 4) {
          int r = lo + (tid >> 2), q = tid & 3;
          float s1 = 0.f, s2 = 0.f;
          const u64* b0 = P.statsG + (size_t)par * 128 * 48 + (size_t)(q * 32) * 48 + r;
          #pragma unroll 8
          for (int w = 0; w < 32; ++w) {
            union { u64 u; float f[2]; } c; c.u = aldu(b0 + (size_t)w * 48);
            s1 += c.f[0]; s2 += c.f[1];
          }
          mbuf[tid][0] = s1; mbuf[tid][1] = s2;
        }
        __syncthreads();
        if (tid < n) {
          int r = lo + tid;
          float s1 = mbuf[tid*4][0] + mbuf[tid*4+1][0] + mbuf[tid*4+2][0] + mbuf[tid*4+3][0];
          float s2 = mbuf[tid*4][1] + mbuf[tid*4+1][1] + mbuf[tid*4+2][1] + mbuf[tid*4+3][1];
          float m = s1 * invD;
          float rs = rsqrtf(s2 * invD - m * m + EPSV);
          union { u64 u; float f[2]; } c; c.f[0] = m; c.f[1] = rs;
          astu(P.sredG + (size_t)par * 48 + r, c.u);
        }
        asm volatile("s_waitcnt vmcnt(0)" ::: "memory");
        __syncthreads();
      }
      int pub = good ? e : (1 << 30);
      if (tid < 8) asti(P.rel + tid * 16, pub);
      return good;
    };

    if (!mevent(1, 0, 0, 0.f, 0)) return;   // prologue
    int rr = 0;
    #pragma unroll 1
    for (int t = 0; t < 256; ++t) {
      #pragma unroll 1
      for (int nn = 0; nn < 3; ++nn) {
        ++rr;  // round A
        if (!mevent(2*rr, 0, 48, 1.f/1024.f, rr & 1)) return;
        if (!mevent(2*rr + 1, 0, 0, 0.f, 0)) return;
        #pragma unroll 1
        for (int it = 1; it < 5; ++it) {
          ++rr;  // inner
          if (!mevent(2*rr, 24, 24, 1.f/1024.f, rr & 1)) return;
          if (!mevent(2*rr + 1, 0, 0, 0.f, 0)) return;
        }
        ++rr;  // high
        if (!mevent(2*rr, 0, 48, 1.f/768.f, rr & 1)) return;
        if (!mevent(2*rr + 1, 0, 0, 0.f, 0)) return;
      }
    }
    return;
  }

  // ================= worker =================
  __shared__ float WhS[24 * 1024];   // low_Wh slice [c][k]
  __shared__ float Bb[8 * 1024];     // staged operand [b][k] (hl or hh)
  __shared__ float XW[24 * 8];       // x @ Wi_x for own 24 cols (per token)
  __shared__ float xiNs[24 * 8];     // normalized xi, kept across inner iters
  __shared__ float stg[2][24 * 8];   // raw (bias-added) GEMM outputs
  __shared__ float sred[96];         // (m, rs) per (set,g,b)
  __shared__ float xm[8], xrs[8];
  __shared__ int idsh[8];
  __shared__ int okf;

  const int wg = blockIdx.x;
  const int ks = tid & 31, cg = tid >> 5;
  const int lj8 = wg * 8, lj6 = wg * 6;

  auto arrive = [&](int e) {
    asm volatile("s_waitcnt vmcnt(0)" ::: "memory");
    __syncthreads();
    if (tid == 0) asti(P.arr + wg, e);
  };
  auto wwait = [&](int e) -> bool {
    if (tid == 0) {
      const int* rp = P.rel + (wg & 7) * 16;
      int lim = 1 << 21, v = 0;
      do {
        v = aldi(rp);
        if (v >= e) break;
        __builtin_amdgcn_s_sleep(2);
      } while (--lim);
      okf = (lim != 0 && v < (1 << 29)) ? 1 : 0;
    }
    __syncthreads();
    return okf != 0;
  };

  // ---- staging via u64 agent loads into LDS [b][1024] ----
  auto stage_hl = [&]() {
    float2 ta[8], tb[8];
    #pragma unroll
    for (int i = 0; i < 8; ++i) {
      const float* p = &P.hl[i * 1024 + tid * 4];
      ta[i] = ald2(p); tb[i] = ald2(p + 2);
    }
    #pragma unroll
    for (int i = 0; i < 8; ++i) {
      float4 v; v.x = ta[i].x; v.y = ta[i].y; v.z = tb[i].x; v.w = tb[i].y;
      *(float4*)&Bb[i * 1024 + tid * 4] = v;
    }
  };
  auto stage_hh = [&]() {
    float2 ta[6], tb[6]; int bi[6], ki[6];
    #pragma unroll
    for (int i = 0; i < 6; ++i) {
      int c = i * 256 + tid; int b = c / 192; int k = (c - b * 192) * 4;
      bi[i] = b; ki[i] = k;
      const float* p = &P.hh[b * 768 + k];
      ta[i] = ald2(p); tb[i] = ald2(p + 2);
    }
    #pragma unroll
    for (int i = 0; i < 6; ++i) {
      float4 v; v.x = ta[i].x; v.y = ta[i].y; v.z = tb[i].x; v.w = tb[i].y;
      *(float4*)&Bb[bi[i] * 1024 + ki[i]] = v;
    }
  };

  // ---- GEMMs: thread (cg,ks) owns 3 cols, k = i*128 + ks*4 ----
  auto gemm_lowh = [&](float (&acc)[3][8]) {
    const int c0 = cg * 3;
    const float* w0p = &WhS[(c0 + 0) * 1024];
    const float* w1p = &WhS[(c0 + 1) * 1024];
    const float* w2p = &WhS[(c0 + 2) * 1024];
    #pragma unroll
    for (int i = 0; i < 8; ++i) {
      int k = i * 128 + ks * 4;
      float4 w0 = *(const float4*)&w0p[k];
      float4 w1 = *(const float4*)&w1p[k];
      float4 w2 = *(const float4*)&w2p[k];
      #pragma unroll
      for (int b = 0; b < 8; ++b) {
        float4 h = *(const float4*)&Bb[b * 1024 + k];
        acc[0][b] += w0.x*h.x + w0.y*h.y + w0.z*h.z + w0.w*h.w;
        acc[1][b] += w1.x*h.x + w1.y*h.y + w1.z*h.z + w1.w*h.w;
        acc[2][b] += w2.x*h.x + w2.y*h.y + w2.z*h.z + w2.w*h.w;
      }
    }
  };
  auto gemm_xih = [&](float (&acc)[3][8]) {   // h_h part of xi: K=768 over Bb=hh
    const float* wp[3];
    #pragma unroll
    for (int cc = 0; cc < 3; ++cc) {
      int c = cg * 3 + cc; int g = c >> 3, jj = c & 7;
      wp[cc] = P.WiT + ((size_t)g * 1024 + lj8 + jj) * 1536 + 768;
    }
    #pragma unroll
    for (int i = 0; i < 6; ++i) {
      int k = i * 128 + ks * 4;
      float4 w0 = *(const float4*)&wp[0][k];
      float4 w1 = *(const float4*)&wp[1][k];
      float4 w2 = *(const float4*)&wp[2][k];
      #pragma unroll
      for (int b = 0; b < 8; ++b) {
        float4 h = *(const float4*)&Bb[b * 1024 + k];
        acc[0][b] += w0.x*h.x + w0.y*h.y + w0.z*h.z + w0.w*h.w;
        acc[1][b] += w1.x*h.x + w1.y*h.y + w1.z*h.z + w1.w*h.w;
        acc[2][b] += w2.x*h.x + w2.y*h.y + w2.z*h.z + w2.w*h.w;
      }
    }
  };
  auto gemm_hxi = [&](float (&acc)[3][8]) {  // K=1024 over Bb=hl, 18 cols
    if (cg >= 6) return;
    const float* wp[3];
    #pragma unroll
    for (int cc = 0; cc < 3; ++cc) {
      int c = cg * 3 + cc; int g = c / 6, jj = c % 6;
      wp[cc] = P.hWiT + ((size_t)g * 768 + lj6 + jj) * 1024;
    }
    #pragma unroll
    for (int i = 0; i < 8; ++i) {
      int k = i * 128 + ks * 4;
      float4 w0 = *(const float4*)&wp[0][k];
      float4 w1 = *(const float4*)&wp[1][k];
      float4 w2 = *(const float4*)&wp[2][k];
      #pragma unroll
      for (int b = 0; b < 8; ++b) {
        float4 h = *(const float4*)&Bb[b * 1024 + k];
        acc[0][b] += w0.x*h.x + w0.y*h.y + w0.z*h.z + w0.w*h.w;
        acc[1][b] += w1.x*h.x + w1.y*h.y + w1.z*h.z + w1.w*h.w;
        acc[2][b] += w2.x*h.x + w2.y*h.y + w2.z*h.z + w2.w*h.w;
      }
    }
  };
  auto gemm_hhh = [&](float (&acc)[3][8]) {  // K=768 over Bb=hh, 18 cols
    if (cg >= 6) return;
    const float* wp[3];
    #pragma unroll
    for (int cc = 0; cc < 3; ++cc) {
      int c = cg * 3 + cc; int g = c / 6, jj = c % 6;
      wp[cc] = P.hWhT + ((size_t)g * 768 + lj6 + jj) * 768;
    }
    #pragma unroll
    for (int i = 0; i < 6; ++i) {
      int k = i * 128 + ks * 4;
      float4 w0 = *(const float4*)&wp[0][k];
      float4 w1 = *(const float4*)&wp[1][k];
      float4 w2 = *(const float4*)&wp[2][k];
      #pragma unroll
      for (int b = 0; b < 8; ++b) {
        float4 h = *(const float4*)&Bb[b * 1024 + k];
        acc[0][b] += w0.x*h.x + w0.y*h.y + w0.z*h.z + w0.w*h.w;
        acc[1][b] += w1.x*h.x + w1.y*h.y + w1.z*h.z + w1.w*h.w;
        acc[2][b] += w2.x*h.x + w2.y*h.y + w2.z*h.z + w2.w*h.w;
      }
    }
  };

  auto redstage = [&](float (&acc)[3][8], int set, const float* bias, int dim,
                      int perg, int jb, bool addXW) {
    #pragma unroll
    for (int cc = 0; cc < 3; ++cc)
      #pragma unroll
      for (int b = 0; b < 8; ++b) {
        float v = acc[cc][b];
        #pragma unroll
        for (int m = 1; m < 32; m <<= 1) v += __shfl_xor(v, m, 64);
        acc[cc][b] = v;
      }
    if ((tid & 31) == 0) {
      int cgl = tid >> 5;
      #pragma unroll
      for (int cc = 0; cc < 3; ++cc) {
        int c = cgl * 3 + cc;
        if (c < perg * 3) {
          int g = (perg == 8) ? (c >> 3) : (c / 6);
          int jj = (perg == 8) ? (c & 7) : (c % 6);
          float bs = bias[g * dim + jb + jj];
          #pragma unroll
          for (int b = 0; b < 8; ++b) {
            float v = acc[cc][b] + bs;
            if (addXW) v += XW[c * 8 + b];
            stg[set][c * 8 + b] = v;
          }
        }
      }
    }
  };

  // private (s1,s2) partial -> statsG[par][wg][set*24 + g*8+b]
  auto stats_put = [&](int par, int set, int perg) {
    if (tid < 24) {
      int g = tid >> 3, b = tid & 7;
      float s1 = 0.f, s2 = 0.f;
      for (int jj = 0; jj < perg; ++jj) {
        float v = stg[set][(g * perg + jj) * 8 + b];
        s1 += v; s2 += v * v;
      }
      union { u64 u; float f[2]; } c; c.f[0] = s1; c.f[1] = s2;
      astu(P.statsG + ((size_t)par * 128 + wg) * 48 + set * 24 + tid, c.u);
    }
  };
  // read master-reduced (m, rs)
  auto sred_read = [&](int par, int lo, int n) {
    if (tid < n) {
      int row = lo + tid;
      union { u64 u; float f[2]; } c;
      c.u = aldu(P.sredG + (size_t)par * 48 + row);
      int set = row / 24, p = row % 24, g = p >> 3, b = p & 7;
      sred[set * 48 + g * 16 + b * 2] = c.f[0];
      sred[set * 48 + g * 16 + b * 2 + 1] = c.f[1];
    }
    __syncthreads();
  };

  auto gate_low = [&](bool isA) {
    if (tid < 64) {
      int jj = tid & 7, b = tid >> 3; int j = lj8 + jj;
      float xin[3], hin[3];
      #pragma unroll
      for (int g = 0; g < 3; ++g) {
        int c = g * 8 + jj;
        if (isA) {
          float m = sred[g * 16 + b * 2], rs = sred[g * 16 + b * 2 + 1];
          float v = (stg[0][c * 8 + b] - m) * rs * P.llig[g * 1024 + j] + P.llib[g * 1024 + j];
          xiNs[c * 8 + b] = v; xin[g] = v;
        } else {
          xin[g] = xiNs[c * 8 + b];
        }
        float m2 = sred[48 + g * 16 + b * 2], rs2 = sred[48 + g * 16 + b * 2 + 1];
        hin[g] = (stg[1][c * 8 + b] - m2) * rs2 * P.llhg[g * 1024 + j] + P.llhb[g * 1024 + j];
      }
      float rg = sigm(xin[0] + hin[0]);
      float zg = sigm(xin[1] + hin[1]);
      float ng = tanh_f(xin[2] + rg * hin[2]);
      float hold = Bb[b * 1024 + j];
      ast(&P.hl[b * 1024 + j], (1.f - zg) * ng + zg * hold);
    }
  };

  auto gate_high = [&](int t, int nn) {
    if (tid < 48) {
      int jj = tid % 6, b = tid / 6; int j = lj6 + jj;
      float xin[3], hin[3];
      #pragma unroll
      for (int g = 0; g < 3; ++g) {
        int c = g * 6 + jj;
        float m = sred[g * 16 + b * 2], rs = sred[g * 16 + b * 2 + 1];
        xin[g] = (stg[0][c * 8 + b] - m) * rs * P.hlig[g * 768 + j] + P.hlib[g * 768 + j];
        float m2 = sred[48 + g * 16 + b * 2], rs2 = sred[48 + g * 16 + b * 2 + 1];
        hin[g] = (stg[1][c * 8 + b] - m2) * rs2 * P.hlhg[g * 768 + j] + P.hlhb[g * 768 + j];
      }
      float rg = sigm(xin[0] + hin[0]);
      float zg = sigm(xin[1] + hin[1]);
      float ng = tanh_f(xin[2] + rg * hin[2]);
      float hold = Bb[b * 1024 + j];
      float hv = (1.f - zg) * ng + zg * hold;
      ast(&P.hh[b * 768 + j], hv);
      if (nn == 2) P.hist[((size_t)t * 8 + b) * 768 + j] = __float2bfloat16(hv);
    }
  };

  // per token: LN stats of x + XW = LN(x) @ Wi_x (own 24 cols, all local)
  auto xfun = [&](int tt) {
    int b = tid >> 5, u = tid & 31;
    if (tid < 8) idsh[tid] = P.ids[tid * 256 + tt];
    int id = P.ids[b * 256 + tt];
    const float* e = P.emb + (size_t)id * 768;
    float s1 = 0.f, s2 = 0.f;
    #pragma unroll
    for (int q = 0; q < 24; q += 4) {
      float4 v = *(const float4*)&e[u * 24 + q];
      s1 += v.x + v.y + v.z + v.w;
      s2 += v.x*v.x + v.y*v.y + v.z*v.z + v.w*v.w;
    }
    #pragma unroll
    for (int m = 1; m < 32; m <<= 1) { s1 += __shfl_xor(s1, m, 64); s2 += __shfl_xor(s2, m, 64); }
    if (u == 0) { float mm = s1 / 768.f; xm[b] = mm; xrs[b] = rsqrtf(s2 / 768.f - mm * mm + EPSV); }
    __syncthreads();
    float acc[3][8] = {};
    const float* wp[3];
    #pragma unroll
    for (int cc = 0; cc < 3; ++cc) {
      int c = cg * 3 + cc; int g = c >> 3, jj = c & 7;
      wp[cc] = P.WiT + ((size_t)g * 1024 + lj8 + jj) * 1536;
    }
    int idv[8];
    #pragma unroll
    for (int bb = 0; bb < 8; ++bb) idv[bb] = idsh[bb];
    #pragma unroll
    for (int i = 0; i < 6; ++i) {
      int k = i * 128 + ks * 4;
      float4 w0 = *(const float4*)&wp[0][k];
      float4 w1 = *(const float4*)&wp[1][k];
      float4 w2 = *(const float4*)&wp[2][k];
      float4 gam = *(const float4*)&P.lng[k];
      float4 bet = *(const float4*)&P.lnb[k];
      #pragma unroll
      for (int bb = 0; bb < 8; ++bb) {
        float4 xv = *(const float4*)&P.emb[(size_t)idv[bb] * 768 + k];
        float4 xn;
        xn.x = (xv.x - xm[bb]) * xrs[bb] * gam.x + bet.x;
        xn.y = (xv.y - xm[bb]) * xrs[bb] * gam.y + bet.y;
        xn.z = (xv.z - xm[bb]) * xrs[bb] * gam.z + bet.z;
        xn.w = (xv.w - xm[bb]) * xrs[bb] * gam.w + bet.w;
        acc[0][bb] += w0.x*xn.x + w0.y*xn.y + w0.z*xn.z + w0.w*xn.w;
        acc[1][bb] += w1.x*xn.x + w1.y*xn.y + w1.z*xn.z + w1.w*xn.w;
        acc[2][bb] += w2.x*xn.x + w2.y*xn.y + w2.z*xn.z + w2.w*xn.w;
      }
    }
    #pragma unroll
    for (int cc = 0; cc < 3; ++cc)
      #pragma unroll
      for (int bb = 0; bb < 8; ++bb) {
        float v = acc[cc][bb];
        #pragma unroll
        for (int m = 1; m < 32; m <<= 1) v += __shfl_xor(v, m, 64);
        acc[cc][bb] = v;
      }
    if ((tid & 31) == 0) {
      int cgl = tid >> 5;
      #pragma unroll
      for (int cc = 0; cc < 3; ++cc)
        #pragma unroll
        for (int bb = 0; bb < 8; ++bb)
          XW[(cgl * 3 + cc) * 8 + bb] = acc[cc][bb];
    }
    __syncthreads();
  };

  // =================== prologue: weight transposes ===================
  #pragma unroll 1
  for (int g = 0; g < 3; ++g)
    for (int it = 0; it < 6; ++it) {   // low_Wi [3][1536][1024] -> WiT[g][j][k]
      int k = it * 256 + tid;
      const float* src = P.lWi + ((size_t)g * 1536 + k) * 1024 + lj8;
      float4 v0 = *(const float4*)src; float4 v1 = *(const float4*)(src + 4);
      float vv[8] = {v0.x, v0.y, v0.z, v0.w, v1.x, v1.y, v1.z, v1.w};
      for (int jj = 0; jj < 8; ++jj)
        P.WiT[((size_t)g * 1024 + lj8 + jj) * 1536 + k] = vv[jj];
    }
  #pragma unroll 1
  for (int g = 0; g < 3; ++g)
    for (int it = 0; it < 4; ++it) {   // high_Wi [3][1024][768] -> hWiT[g][j][k]
      int k = it * 256 + tid;
      const float* src = P.hWi + ((size_t)g * 1024 + k) * 768 + lj6;
      float2 a = *(const float2*)src, b2v = *(const float2*)(src + 2), c2v = *(const float2*)(src + 4);
      float vv[6] = {a.x, a.y, b2v.x, b2v.y, c2v.x, c2v.y};
      for (int jj = 0; jj < 6; ++jj)
        P.hWiT[((size_t)g * 768 + lj6 + jj) * 1024 + k] = vv[jj];
    }
  #pragma unroll 1
  for (int g = 0; g < 3; ++g)
    for (int it = 0; it < 3; ++it) {   // high_Wh [3][768][768] -> hWhT[g][j][k]
      int k = it * 256 + tid;
      const float* src = P.hWh + ((size_t)g * 768 + k) * 768 + lj6;
      float2 a = *(const float2*)src, b2v = *(const float2*)(src + 2), c2v = *(const float2*)(src + 4);
      float vv[6] = {a.x, a.y, b2v.x, b2v.y, c2v.x, c2v.y};
      for (int jj = 0; jj < 6; ++jj)
        P.hWhT[((size_t)g * 768 + lj6 + jj) * 768 + k] = vv[jj];
    }
  #pragma unroll 1
  for (int g = 0; g < 3; ++g)
    for (int it = 0; it < 4; ++it) {   // low_Wh slice -> LDS
      int k = it * 256 + tid;
      const float* src = P.lWh + ((size_t)g * 1024 + k) * 1024 + lj8;
      float4 v0 = *(const float4*)src; float4 v1 = *(const float4*)(src + 4);
      float vv[8] = {v0.x, v0.y, v0.z, v0.w, v1.x, v1.y, v1.z, v1.w};
      for (int jj = 0; jj < 8; ++jj) WhS[(g * 8 + jj) * 1024 + k] = vv[jj];
    }
  __syncthreads();
  xfun(0);
  arrive(1);
  bool alive = wwait(1);

  // =================== main recurrence ===================
  int rr = 0;
  #pragma unroll 1
  for (int t = 0; alive && t < 256; ++t) {
    #pragma unroll 1
    for (int nn = 0; nn < 3 && alive; ++nn) {
      // ---- round A: xi (XW + hh@Wi_h) + inner iteration 1 ----
      ++rr; int par = rr & 1;
      {
        stage_hh(); __syncthreads();
        float accX[3][8] = {};
        gemm_xih(accX);
        redstage(accX, 0, P.lbi, 1024, 8, lj8, true);
        __syncthreads();
        stage_hl(); __syncthreads();
        float accH[3][8] = {};
        gemm_lowh(accH);
        redstage(accH, 1, P.lbh, 1024, 8, lj8, false);
        __syncthreads();
        stats_put(par, 0, 8); stats_put(par, 1, 8);
        arrive(2 * rr);
        alive = wwait(2 * rr); if (!alive) break;
        sred_read(par, 0, 48);
        gate_low(true);
        arrive(2 * rr + 1);
        alive = wwait(2 * rr + 1); if (!alive) break;
      }
      // ---- inner iterations 2..5 ----
      #pragma unroll 1
      for (int it = 1; it < 5 && alive; ++it) {
        ++rr; par = rr & 1;
        stage_hl(); __syncthreads();
        float acc2[3][8] = {};
        gemm_lowh(acc2);
        redstage(acc2, 1, P.lbh, 1024, 8, lj8, false);
        __syncthreads();
        stats_put(par, 1, 8);
        arrive(2 * rr);
        alive = wwait(2 * rr); if (!alive) break;
        sred_read(par, 24, 24);
        gate_low(false);
        arrive(2 * rr + 1);
        alive = wwait(2 * rr + 1); if (!alive) break;
      }
      if (!alive) break;
      // ---- high GRU round ----
      ++rr; par = rr & 1;
      {
        stage_hl(); __syncthreads();
        float aX[3][8] = {};
        gemm_hxi(aX);
        redstage(aX, 0, P.hbi, 768, 6, lj6, false);
        __syncthreads();
        stage_hh(); __syncthreads();
        float aH[3][8] = {};
        gemm_hhh(aH);
        redstage(aH, 1, P.hbh, 768, 6, lj6, false);
        __syncthreads();
        stats_put(par, 0, 6); stats_put(par, 1, 6);
        arrive(2 * rr);
        alive = wwait(2 * rr); if (!alive) break;
        sred_read(par, 0, 48);
        gate_high(t, nn);
        if (nn == 2 && t < 255) { __syncthreads(); xfun(t + 1); }
        arrive(2 * rr + 1);
        alive = wwait(2 * rr + 1); if (!alive) break;
      }
    }
  }
}

// =================== Wout transpose + bf16 convert ===================
__global__ void __launch_bounds__(256) wout_t(const float* __restrict__ W,
                                              __hip_bfloat16* __restrict__ WT) {
  __shared__ float T[64][65];
  int n0 = blockIdx.x * 64, k0 = blockIdx.y * 64;
  int tid = threadIdx.x;
  int lane16 = tid & 15, grp = tid >> 4;
  #pragma unroll
  for (int i = 0; i < 4; ++i) {
    int kl = i * 16 + grp; int nl = lane16 * 4;
    float4 v = *(const float4*)&W[(size_t)(k0 + kl) * 32000 + n0 + nl];
    T[kl][nl] = v.x; T[kl][nl + 1] = v.y; T[kl][nl + 2] = v.z; T[kl][nl + 3] = v.w;
  }
  __syncthreads();
  #pragma unroll
  for (int i = 0; i < 4; ++i) {
    int nl = i * 16 + grp; int kl = lane16 * 4;
    union { ushort4 v; __hip_bfloat16 h[4]; } u;
    for (int q = 0; q < 4; ++q) u.h[q] = __float2bfloat16(T[kl + q][nl]);
    *(ushort4*)&WT[(size_t)(n0 + nl) * 768 + k0 + kl] = u.v;
  }
}

// =================== logits GEMM: [2048,768] x [768,32000]^T-stored ===================
__global__ void __launch_bounds__(256) logits_gemm(const __hip_bfloat16* __restrict__ Ah,
                                                   const __hip_bfloat16* __restrict__ Bt,
                                                   const float* __restrict__ bias,
                                                   float* __restrict__ out) {
  __shared__ short As[128 * 64];
  __shared__ short Bs[128 * 64];
  int m0 = blockIdx.y * 128, n0 = blockIdx.x * 128;
  int tid = threadIdx.x, lane = tid & 63, w = tid >> 6;
  int wr = w >> 1, wc = w & 1;
  int r16 = lane & 15, khalf = (lane >> 4) * 8;
  f32x4 acc[4][4];
  #pragma unroll
  for (int i = 0; i < 4; ++i)
    #pragma unroll
    for (int j = 0; j < 4; ++j)
      #pragma unroll
      for (int q = 0; q < 4; ++q) acc[i][j][q] = 0.f;

  for (int kt = 0; kt < 12; ++kt) {
    int k0 = kt * 64;
    __syncthreads();
    #pragma unroll
    for (int it = 0; it < 4; ++it) {
      int f = it * 2048 + tid * 8; int row = f >> 6, col = f & 63;
      *(uint4*)&As[f] = *(const uint4*)&Ah[(size_t)(m0 + row) * 768 + k0 + col];
      *(uint4*)&Bs[f] = *(const uint4*)&Bt[(size_t)(n0 + row) * 768 + k0 + col];
    }
    __syncthreads();
    #pragma unroll
    for (int kk = 0; kk < 64; kk += 32) {
      short8 af[4], bfr[4];
      #pragma unroll
      for (int i = 0; i < 4; ++i)
        af[i] = *(short8*)&As[(wr * 64 + i * 16 + r16) * 64 + kk + khalf];
      #pragma unroll
      for (int j = 0; j < 4; ++j)
        bfr[j] = *(short8*)&Bs[(wc * 64 + j * 16 + r16) * 64 + kk + khalf];
      #pragma unroll
      for (int i = 0; i < 4; ++i)
        #pragma unroll
        for (int j = 0; j < 4; ++j)
          acc[i][j] = __builtin_amdgcn_mfma_f32_16x16x32_bf16(af[i], bfr[j], acc[i][j], 0, 0, 0);
    }
  }
  #pragma unroll
  for (int i = 0; i < 4; ++i)
    #pragma unroll
    for (int j = 0; j < 4; ++j)
      #pragma unroll
      for (int q = 0; q < 4; ++q) {
        int m = m0 + wr * 64 + i * 16 + ((lane >> 4) * 4 + q);
        int n = n0 + wc * 64 + j * 16 + (lane & 15);
        out[(size_t)(m & 7) * 8192000 + (size_t)(m >> 3) * 32000 + n] =
            acc[i][j][q] + bias[n];
      }
}

extern "C" void kernel_launch(void* const* d_in, const int* in_sizes, int n_in,
                              void* d_out, int out_size, void* d_ws, size_t ws_size,
                              hipStream_t stream) {
  (void)in_sizes; (void)n_in; (void)out_size; (void)ws_size;
  char* wsb = (char*)d_ws;
  size_t off = 0;
  auto take = [&](size_t bytes) -> void* {
    void* p = wsb + off;
    off += (bytes + 1023) & ~(size_t)1023;
    return p;
  };
  int* arr      = (int*)take((size_t)128 * 4);            // worker epoch slots
  int* rel      = (int*)take((size_t)8 * 16 * 4);         // release lines (sharded)
  float* hl     = (float*)take((size_t)8 * 1024 * 4);
  float* hh     = (float*)take((size_t)8 * 768 * 4);
  size_t state_bytes = off;                               // ~58 KB -> memset
  u64* statsG   = (u64*)take((size_t)2 * 128 * 48 * 8);   // private stats partials
  u64* sredG    = (u64*)take((size_t)2 * 48 * 8);         // master-reduced (m, rs)
  __hip_bfloat16* hist = (__hip_bfloat16*)take((size_t)2048 * 768 * 2);
  float* WiT    = (float*)take((size_t)3 * 1024 * 1536 * 4);
  float* hWiT   = (float*)take((size_t)3 * 768 * 1024 * 4);
  float* hWhT   = (float*)take((size_t)3 * 768 * 768 * 4);
  __hip_bfloat16* WoutT = (__hip_bfloat16*)take((size_t)32000 * 768 * 2);

  hipMemsetAsync(d_ws, 0, state_bytes, stream);  // arr/rel/hl/hh = 0

  wout_t<<<dim3(500, 12), 256, 0, stream>>>((const float*)d_in[20], WoutT);

  PArgs A;
  A.ids = (const int*)d_in[0];   A.emb = (const float*)d_in[1];
  A.lng = (const float*)d_in[2]; A.lnb = (const float*)d_in[3];
  A.lWi = (const float*)d_in[4]; A.lbi = (const float*)d_in[5];
  A.lWh = (const float*)d_in[6]; A.lbh = (const float*)d_in[7];
  A.llig = (const float*)d_in[8];  A.llib = (const float*)d_in[9];
  A.llhg = (const float*)d_in[10]; A.llhb = (const float*)d_in[11];
  A.hWi = (const float*)d_in[12];  A.hbi = (const float*)d_in[13];
  A.hWh = (const float*)d_in[14];  A.hbh = (const float*)d_in[15];
  A.hlig = (const float*)d_in[16]; A.hlib = (const float*)d_in[17];
  A.hlhg = (const float*)d_in[18]; A.hlhb = (const float*)d_in[19];
  A.arr = arr; A.rel = rel; A.statsG = statsG; A.sredG = sredG;
  A.hl = hl; A.hh = hh;
  A.hist = hist; A.WiT = WiT; A.hWiT = hWiT; A.hWhT = hWhT;

  hrm_recur<<<NWG + 1, NTH, 0, stream>>>(A);

  logits_gemm<<<dim3(250, 16), 256, 0, stream>>>(hist, WoutT,
                                                 (const float*)d_in[21],
                                                 (float*)d_out);
}

// Round 6
// 70977.765 us; speedup vs baseline: 2.3501x; 1.1468x over previous
//
#include <hip/hip_runtime.h>
#include <hip/hip_bf16.h>

// HRM-LM on MI355X — owner-gating + master-release sync + replicated h.
// 128 worker WGs (1/CU) + 1 dedicated master WG.
// h-state is kept in 4 LLC replicas: gate owners write all 4, stagers read
// replica (wg&3) with 16B sc1 loads (inline asm, batched) -> ~16x fewer LLC
// transactions on the h broadcast vs round 5. Master reduces LN stats from
// private per-WG partials (16B loads) and publishes (mean, rsqrt).
// xi = XW (x@Wi_x once per token, local) + h_h@Wi_h. low_Wh LDS-resident.
// h_h history logged bf16; logits via deferred bf16 MFMA GEMM.

#define NWG 128
#define NTH 256
#define EPSV 1e-5f

typedef __attribute__((ext_vector_type(4))) float f32x4;
typedef __attribute__((ext_vector_type(8))) short short8;
typedef unsigned long long u64;

struct PArgs {
  const int* ids; const float* emb; const float* lng; const float* lnb;
  const float* lWi; const float* lbi; const float* lWh; const float* lbh;
  const float* llig; const float* llib; const float* llhg; const float* llhb;
  const float* hWi; const float* hbi; const float* hWh; const float* hbh;
  const float* hlig; const float* hlib; const float* hlhg; const float* hlhb;
  int* arr; int* rel; u64* statsG; u64* sredG; float* hlR; float* hhR;
  __hip_bfloat16* hist; float* WiT; float* hWiT; float* hWhT;
};

__device__ __forceinline__ float sigm(float x) { return 1.f / (1.f + __expf(-x)); }
__device__ __forceinline__ float tanh_f(float x) {
  x = fminf(15.f, fmaxf(-15.f, x));
  float e = __expf(2.f * x);
  return (e - 1.f) / (e + 1.f);
}
// agent-scope (sc1, LLC-coherent) scalar ops
__device__ __forceinline__ void ast(float* p, float v) {
  __hip_atomic_store(p, v, __ATOMIC_RELAXED, __HIP_MEMORY_SCOPE_AGENT);
}
__device__ __forceinline__ int aldi(const int* p) {
  return __hip_atomic_load(p, __ATOMIC_RELAXED, __HIP_MEMORY_SCOPE_AGENT);
}
__device__ __forceinline__ u64 aldu(const u64* p) {
  return __hip_atomic_load(p, __ATOMIC_RELAXED, __HIP_MEMORY_SCOPE_AGENT);
}
__device__ __forceinline__ void astu(u64* p, u64 v) {
  __hip_atomic_store(p, v, __ATOMIC_RELAXED, __HIP_MEMORY_SCOPE_AGENT);
}
__device__ __forceinline__ void asti(int* p, int v) {
  __hip_atomic_store(p, v, __ATOMIC_RELAXED, __HIP_MEMORY_SCOPE_AGENT);
}
// batched 16B agent-coherent loads: issue N dwordx4 sc1, single vmcnt drain
__device__ __forceinline__ void ald4x2(const float* p0, const float* p1,
                                       float4& a, float4& b) {
  asm volatile(
      "global_load_dwordx4 %0, %2, off sc1\n\t"
      "global_load_dwordx4 %1, %3, off sc1\n\t"
      "s_waitcnt vmcnt(0)"
      : "=&v"(a), "=&v"(b)
      : "v"(p0), "v"(p1)
      : "memory");
}
__device__ __forceinline__ void ald4x4(const float* p0, const float* p1,
                                       const float* p2, const float* p3,
                                       float4& a, float4& b, float4& c, float4& d) {
  asm volatile(
      "global_load_dwordx4 %0, %4, off sc1\n\t"
      "global_load_dwordx4 %1, %5, off sc1\n\t"
      "global_load_dwordx4 %2, %6, off sc1\n\t"
      "global_load_dwordx4 %3, %7, off sc1\n\t"
      "s_waitcnt vmcnt(0)"
      : "=&v"(a), "=&v"(b), "=&v"(c), "=&v"(d)
      : "v"(p0), "v"(p1), "v"(p2), "v"(p3)
      : "memory");
}
__device__ __forceinline__ void ald4x8(const float* p0, const float* p1,
                                       const float* p2, const float* p3,
                                       const float* p4, const float* p5,
                                       const float* p6, const float* p7,
                                       float4& a, float4& b, float4& c, float4& d,
                                       float4& e, float4& f, float4& g, float4& h) {
  asm volatile(
      "global_load_dwordx4 %0, %8, off sc1\n\t"
      "global_load_dwordx4 %1, %9, off sc1\n\t"
      "global_load_dwordx4 %2, %10, off sc1\n\t"
      "global_load_dwordx4 %3, %11, off sc1\n\t"
      "global_load_dwordx4 %4, %12, off sc1\n\t"
      "global_load_dwordx4 %5, %13, off sc1\n\t"
      "global_load_dwordx4 %6, %14, off sc1\n\t"
      "global_load_dwordx4 %7, %15, off sc1\n\t"
      "s_waitcnt vmcnt(0)"
      : "=&v"(a), "=&v"(b), "=&v"(c), "=&v"(d),
        "=&v"(e), "=&v"(f), "=&v"(g), "=&v"(h)
      : "v"(p0), "v"(p1), "v"(p2), "v"(p3),
        "v"(p4), "v"(p5), "v"(p6), "v"(p7)
      : "memory");
}

__global__ void __launch_bounds__(NTH) hrm_recur(PArgs P) {
  const int tid = threadIdx.x;

  // ================= dedicated sync/reduce master =================
  if (blockIdx.x == NWG) {
    __shared__ float mbuf[192][4];
    __shared__ int mok;
    auto mevent = [&](int e, int lo, int n, float invD, int par) -> bool {
      if (tid < 64) {
        const u64* ap = (const u64*)P.arr + tid;
        int lim = 1 << 22, good = 1;
        for (;;) {
          u64 v = aldu(ap);
          int a0 = (int)(unsigned)(v & 0xffffffffull);
          int a1 = (int)(unsigned)(v >> 32);
          if (__all(a0 >= e && a1 >= e)) break;
          if (--lim == 0) { good = 0; break; }
          __builtin_amdgcn_s_sleep(1);
        }
        if (tid == 0) mok = good;
      }
      __syncthreads();
      bool good = (mok != 0);
      if (good && n > 0) {
        // rows [lo, lo+n), n in {24,48}; row-pairs so each float4 covers 2 rows
        const int rpn = n >> 1;
        const int Q = (n == 48) ? 8 : 16;   // wg buckets
        const int wpq = 128 / Q;            // wgs per bucket (16 or 8)
        if (tid < rpn * Q) {
          int rp = (lo >> 1) + tid / Q, q = tid % Q;
          const float* b0 = (const float*)(P.statsG + (size_t)par * 128 * 48);
          float4 s; s.x = 0.f; s.y = 0.f; s.z = 0.f; s.w = 0.f;
          #pragma unroll
          for (int blk = 0; blk < 2; ++blk) {
            if (blk == 1 && wpq == 8) break;
            int w0 = q * wpq + blk * 8;
            float4 t0,t1,t2,t3,t4,t5,t6,t7;
            ald4x8(b0 + ((size_t)(w0+0)*48 + rp*2)*2, b0 + ((size_t)(w0+1)*48 + rp*2)*2,
                   b0 + ((size_t)(w0+2)*48 + rp*2)*2, b0 + ((size_t)(w0+3)*48 + rp*2)*2,
                   b0 + ((size_t)(w0+4)*48 + rp*2)*2, b0 + ((size_t)(w0+5)*48 + rp*2)*2,
                   b0 + ((size_t)(w0+6)*48 + rp*2)*2, b0 + ((size_t)(w0+7)*48 + rp*2)*2,
                   t0,t1,t2,t3,t4,t5,t6,t7);
            s.x += t0.x+t1.x+t2.x+t3.x+t4.x+t5.x+t6.x+t7.x;
            s.y += t0.y+t1.y+t2.y+t3.y+t4.y+t5.y+t6.y+t7.y;
            s.z += t0.z+t1.z+t2.z+t3.z+t4.z+t5.z+t6.z+t7.z;
            s.w += t0.w+t1.w+t2.w+t3.w+t4.w+t5.w+t6.w+t7.w;
          }
          mbuf[tid][0] = s.x; mbuf[tid][1] = s.y; mbuf[tid][2] = s.z; mbuf[tid][3] = s.w;
        }
        __syncthreads();
        if (tid < n) {
          int rpl = tid >> 1, comp = tid & 1;
          const int Q2 = (n == 48) ? 8 : 16;
          float s1 = 0.f, s2 = 0.f;
          for (int q = 0; q < Q2; ++q) {
            s1 += mbuf[rpl * Q2 + q][comp * 2 + 0];
            s2 += mbuf[rpl * Q2 + q][comp * 2 + 1];
          }
          float m = s1 * invD;
          float rs = rsqrtf(s2 * invD - m * m + EPSV);
          union { u64 u; float f[2]; } c; c.f[0] = m; c.f[1] = rs;
          astu(P.sredG + (size_t)par * 48 + lo + tid, c.u);
        }
        asm volatile("s_waitcnt vmcnt(0)" ::: "memory");
        __syncthreads();
      }
      int pub = good ? e : (1 << 30);
      if (tid < 8) asti(P.rel + tid * 16, pub);
      return good;
    };

    if (!mevent(1, 0, 0, 0.f, 0)) return;   // prologue
    int rr = 0;
    #pragma unroll 1
    for (int t = 0; t < 256; ++t) {
      #pragma unroll 1
      for (int nn = 0; nn < 3; ++nn) {
        ++rr;  // round A
        if (!mevent(2*rr, 0, 48, 1.f/1024.f, rr & 1)) return;
        if (!mevent(2*rr + 1, 0, 0, 0.f, 0)) return;
        #pragma unroll 1
        for (int it = 1; it < 5; ++it) {
          ++rr;  // inner
          if (!mevent(2*rr, 24, 24, 1.f/1024.f, rr & 1)) return;
          if (!mevent(2*rr + 1, 0, 0, 0.f, 0)) return;
        }
        ++rr;  // high
        if (!mevent(2*rr, 0, 48, 1.f/768.f, rr & 1)) return;
        if (!mevent(2*rr + 1, 0, 0, 0.f, 0)) return;
      }
    }
    return;
  }

  // ================= worker =================
  __shared__ float WhS[24 * 1024];   // low_Wh slice [c][k]
  __shared__ float Bb[8 * 1024];     // staged operand [b][k] (hl or hh)
  __shared__ float XW[24 * 8];       // x @ Wi_x for own 24 cols (per token)
  __shared__ float xiNs[24 * 8];     // normalized xi, kept across inner iters
  __shared__ float stg[2][24 * 8];   // raw (bias-added) GEMM outputs
  __shared__ float sred[96];         // (m, rs) per (set,g,b)
  __shared__ float xm[8], xrs[8];
  __shared__ int idsh[8];
  __shared__ int okf;

  const int wg = blockIdx.x;
  const int ks = tid & 31, cg = tid >> 5;
  const int lj8 = wg * 8, lj6 = wg * 6;
  const int rep = wg & 3;

  auto arrive = [&](int e) {
    asm volatile("s_waitcnt vmcnt(0)" ::: "memory");
    __syncthreads();
    if (tid == 0) asti(P.arr + wg, e);
  };
  auto wwait = [&](int e) -> bool {
    if (tid == 0) {
      const int* rp = P.rel + (wg & 7) * 16;
      int lim = 1 << 22, v = 0;
      do {
        v = aldi(rp);
        if (v >= e) break;
        __builtin_amdgcn_s_sleep(1);
      } while (--lim);
      okf = (lim != 0 && v < (1 << 29)) ? 1 : 0;
    }
    __syncthreads();
    return okf != 0;
  };

  // ---- staging from replica (wg&3) via batched 16B sc1 loads ----
  auto stage_hl = [&]() {
    const float* base = P.hlR + (size_t)rep * 8192 + tid * 4;
    float4 t0,t1,t2,t3,t4,t5,t6,t7;
    ald4x8(base + 0*1024, base + 1*1024, base + 2*1024, base + 3*1024,
           base + 4*1024, base + 5*1024, base + 6*1024, base + 7*1024,
           t0,t1,t2,t3,t4,t5,t6,t7);
    *(float4*)&Bb[0*1024 + tid*4] = t0; *(float4*)&Bb[1*1024 + tid*4] = t1;
    *(float4*)&Bb[2*1024 + tid*4] = t2; *(float4*)&Bb[3*1024 + tid*4] = t3;
    *(float4*)&Bb[4*1024 + tid*4] = t4; *(float4*)&Bb[5*1024 + tid*4] = t5;
    *(float4*)&Bb[6*1024 + tid*4] = t6; *(float4*)&Bb[7*1024 + tid*4] = t7;
  };
  auto stage_hh = [&]() {
    const float* base = P.hhR + (size_t)rep * 6144;
    int bi[6], ki[6];
    #pragma unroll
    for (int i = 0; i < 6; ++i) {
      int c = i * 256 + tid; int b = c / 192; int k = (c - b * 192) * 4;
      bi[i] = b; ki[i] = k;
    }
    float4 t0,t1,t2,t3,t4,t5;
    ald4x4(base + bi[0]*768 + ki[0], base + bi[1]*768 + ki[1],
           base + bi[2]*768 + ki[2], base + bi[3]*768 + ki[3], t0,t1,t2,t3);
    ald4x2(base + bi[4]*768 + ki[4], base + bi[5]*768 + ki[5], t4,t5);
    *(float4*)&Bb[bi[0]*1024 + ki[0]] = t0; *(float4*)&Bb[bi[1]*1024 + ki[1]] = t1;
    *(float4*)&Bb[bi[2]*1024 + ki[2]] = t2; *(float4*)&Bb[bi[3]*1024 + ki[3]] = t3;
    *(float4*)&Bb[bi[4]*1024 + ki[4]] = t4; *(float4*)&Bb[bi[5]*1024 + ki[5]] = t5;
  };

  // ---- GEMMs: thread (cg,ks) owns 3 cols, k = i*128 + ks*4 ----
  auto gemm_lowh = [&](float (&acc)[3][8]) {
    const int c0 = cg * 3;
    const float* w0p = &WhS[(c0 + 0) * 1024];
    const float* w1p = &WhS[(c0 + 1) * 1024];
    const float* w2p = &WhS[(c0 + 2) * 1024];
    #pragma unroll
    for (int i = 0; i < 8; ++i) {
      int k = i * 128 + ks * 4;
      float4 w0 = *(const float4*)&w0p[k];
      float4 w1 = *(const float4*)&w1p[k];
      float4 w2 = *(const float4*)&w2p[k];
      #pragma unroll
      for (int b = 0; b < 8; ++b) {
        float4 h = *(const float4*)&Bb[b * 1024 + k];
        acc[0][b] += w0.x*h.x + w0.y*h.y + w0.z*h.z + w0.w*h.w;
        acc[1][b] += w1.x*h.x + w1.y*h.y + w1.z*h.z + w1.w*h.w;
        acc[2][b] += w2.x*h.x + w2.y*h.y + w2.z*h.z + w2.w*h.w;
      }
    }
  };
  auto gemm_xih = [&](float (&acc)[3][8]) {   // h_h part of xi: K=768 over Bb=hh
    const float* wp[3];
    #pragma unroll
    for (int cc = 0; cc < 3; ++cc) {
      int c = cg * 3 + cc; int g = c >> 3, jj = c & 7;
      wp[cc] = P.WiT + ((size_t)g * 1024 + lj8 + jj) * 1536 + 768;
    }
    #pragma unroll
    for (int i = 0; i < 6; ++i) {
      int k = i * 128 + ks * 4;
      float4 w0 = *(const float4*)&wp[0][k];
      float4 w1 = *(const float4*)&wp[1][k];
      float4 w2 = *(const float4*)&wp[2][k];
      #pragma unroll
      for (int b = 0; b < 8; ++b) {
        float4 h = *(const float4*)&Bb[b * 1024 + k];
        acc[0][b] += w0.x*h.x + w0.y*h.y + w0.z*h.z + w0.w*h.w;
        acc[1][b] += w1.x*h.x + w1.y*h.y + w1.z*h.z + w1.w*h.w;
        acc[2][b] += w2.x*h.x + w2.y*h.y + w2.z*h.z + w2.w*h.w;
      }
    }
  };
  auto gemm_hxi = [&](float (&acc)[3][8]) {  // K=1024 over Bb=hl, 18 cols
    if (cg >= 6) return;
    const float* wp[3];
    #pragma unroll
    for (int cc = 0; cc < 3; ++cc) {
      int c = cg * 3 + cc; int g = c / 6, jj = c % 6;
      wp[cc] = P.hWiT + ((size_t)g * 768 + lj6 + jj) * 1024;
    }
    #pragma unroll
    for (int i = 0; i < 8; ++i) {
      int k = i * 128 + ks * 4;
      float4 w0 = *(const float4*)&wp[0][k];
      float4 w1 = *(const float4*)&wp[1][k];
      float4 w2 = *(const float4*)&wp[2][k];
      #pragma unroll
      for (int b = 0; b < 8; ++b) {
        float4 h = *(const float4*)&Bb[b * 1024 + k];
        acc[0][b] += w0.x*h.x + w0.y*h.y + w0.z*h.z + w0.w*h.w;
        acc[1][b] += w1.x*h.x + w1.y*h.y + w1.z*h.z + w1.w*h.w;
        acc[2][b] += w2.x*h.x + w2.y*h.y + w2.z*h.z + w2.w*h.w;
      }
    }
  };
  auto gemm_hhh = [&](float (&acc)[3][8]) {  // K=768 over Bb=hh, 18 cols
    if (cg >= 6) return;
    const float* wp[3];
    #pragma unroll
    for (int cc = 0; cc < 3; ++cc) {
      int c = cg * 3 + cc; int g = c / 6, jj = c % 6;
      wp[cc] = P.hWhT + ((size_t)g * 768 + lj6 + jj) * 768;
    }
    #pragma unroll
    for (int i = 0; i < 6; ++i) {
      int k = i * 128 + ks * 4;
      float4 w0 = *(const float4*)&wp[0][k];
      float4 w1 = *(const float4*)&wp[1][k];
      float4 w2 = *(const float4*)&wp[2][k];
      #pragma unroll
      for (int b = 0; b < 8; ++b) {
        float4 h = *(const float4*)&Bb[b * 1024 + k];
        acc[0][b] += w0.x*h.x + w0.y*h.y + w0.z*h.z + w0.w*h.w;
        acc[1][b] += w1.x*h.x + w1.y*h.y + w1.z*h.z + w1.w*h.w;
        acc[2][b] += w2.x*h.x + w2.y*h.y + w2.z*h.z + w2.w*h.w;
      }
    }
  };

  auto redstage = [&](float (&acc)[3][8], int set, const float* bias, int dim,
                      int perg, int jb, bool addXW) {
    #pragma unroll
    for (int cc = 0; cc < 3; ++cc)
      #pragma unroll
      for (int b = 0; b < 8; ++b) {
        float v = acc[cc][b];
        #pragma unroll
        for (int m = 1; m < 32; m <<= 1) v += __shfl_xor(v, m, 64);
        acc[cc][b] = v;
      }
    if ((tid & 31) == 0) {
      int cgl = tid >> 5;
      #pragma unroll
      for (int cc = 0; cc < 3; ++cc) {
        int c = cgl * 3 + cc;
        if (c < perg * 3) {
          int g = (perg == 8) ? (c >> 3) : (c / 6);
          int jj = (perg == 8) ? (c & 7) : (c % 6);
          float bs = bias[g * dim + jb + jj];
          #pragma unroll
          for (int b = 0; b < 8; ++b) {
            float v = acc[cc][b] + bs;
            if (addXW) v += XW[c * 8 + b];
            stg[set][c * 8 + b] = v;
          }
        }
      }
    }
  };

  // private (s1,s2) partial -> statsG[par][wg][set*24 + g*8+b]
  auto stats_put = [&](int par, int set, int perg) {
    if (tid < 24) {
      int g = tid >> 3, b = tid & 7;
      float s1 = 0.f, s2 = 0.f;
      for (int jj = 0; jj < perg; ++jj) {
        float v = stg[set][(g * perg + jj) * 8 + b];
        s1 += v; s2 += v * v;
      }
      union { u64 u; float f[2]; } c; c.f[0] = s1; c.f[1] = s2;
      astu(P.statsG + ((size_t)par * 128 + wg) * 48 + set * 24 + tid, c.u);
    }
  };
  // read master-reduced (m, rs)
  auto sred_read = [&](int par, int lo, int n) {
    if (tid < n) {
      int row = lo + tid;
      union { u64 u; float f[2]; } c;
      c.u = aldu(P.sredG + (size_t)par * 48 + row);
      int set = row / 24, p = row % 24, g = p >> 3, b = p & 7;
      sred[set * 48 + g * 16 + b * 2] = c.f[0];
      sred[set * 48 + g * 16 + b * 2 + 1] = c.f[1];
    }
    __syncthreads();
  };

  auto gate_low = [&](bool isA) {
    if (tid < 64) {
      int jj = tid & 7, b = tid >> 3; int j = lj8 + jj;
      float xin[3], hin[3];
      #pragma unroll
      for (int g = 0; g < 3; ++g) {
        int c = g * 8 + jj;
        if (isA) {
          float m = sred[g * 16 + b * 2], rs = sred[g * 16 + b * 2 + 1];
          float v = (stg[0][c * 8 + b] - m) * rs * P.llig[g * 1024 + j] + P.llib[g * 1024 + j];
          xiNs[c * 8 + b] = v; xin[g] = v;
        } else {
          xin[g] = xiNs[c * 8 + b];
        }
        float m2 = sred[48 + g * 16 + b * 2], rs2 = sred[48 + g * 16 + b * 2 + 1];
        hin[g] = (stg[1][c * 8 + b] - m2) * rs2 * P.llhg[g * 1024 + j] + P.llhb[g * 1024 + j];
      }
      float rg = sigm(xin[0] + hin[0]);
      float zg = sigm(xin[1] + hin[1]);
      float ng = tanh_f(xin[2] + rg * hin[2]);
      float hold = Bb[b * 1024 + j];
      float hv = (1.f - zg) * ng + zg * hold;
      #pragma unroll
      for (int rp = 0; rp < 4; ++rp) ast(&P.hlR[rp * 8192 + b * 1024 + j], hv);
    }
  };

  auto gate_high = [&](int t, int nn) {
    if (tid < 48) {
      int jj = tid % 6, b = tid / 6; int j = lj6 + jj;
      float xin[3], hin[3];
      #pragma unroll
      for (int g = 0; g < 3; ++g) {
        int c = g * 6 + jj;
        float m = sred[g * 16 + b * 2], rs = sred[g * 16 + b * 2 + 1];
        xin[g] = (stg[0][c * 8 + b] - m) * rs * P.hlig[g * 768 + j] + P.hlib[g * 768 + j];
        float m2 = sred[48 + g * 16 + b * 2], rs2 = sred[48 + g * 16 + b * 2 + 1];
        hin[g] = (stg[1][c * 8 + b] - m2) * rs2 * P.hlhg[g * 768 + j] + P.hlhb[g * 768 + j];
      }
      float rg = sigm(xin[0] + hin[0]);
      float zg = sigm(xin[1] + hin[1]);
      float ng = tanh_f(xin[2] + rg * hin[2]);
      float hold = Bb[b * 1024 + j];
      float hv = (1.f - zg) * ng + zg * hold;
      #pragma unroll
      for (int rp = 0; rp < 4; ++rp) ast(&P.hhR[rp * 6144 + b * 768 + j], hv);
      if (nn == 2) P.hist[((size_t)t * 8 + b) * 768 + j] = __float2bfloat16(hv);
    }
  };

  // per token: LN stats of x + XW = LN(x) @ Wi_x (own 24 cols, all local)
  auto xfun = [&](int tt) {
    int b = tid >> 5, u = tid & 31;
    if (tid < 8) idsh[tid] = P.ids[tid * 256 + tt];
    int id = P.ids[b * 256 + tt];
    const float* e = P.emb + (size_t)id * 768;
    float s1 = 0.f, s2 = 0.f;
    #pragma unroll
    for (int q = 0; q < 24; q += 4) {
      float4 v = *(const float4*)&e[u * 24 + q];
      s1 += v.x + v.y + v.z + v.w;
      s2 += v.x*v.x + v.y*v.y + v.z*v.z + v.w*v.w;
    }
    #pragma unroll
    for (int m = 1; m < 32; m <<= 1) { s1 += __shfl_xor(s1, m, 64); s2 += __shfl_xor(s2, m, 64); }
    if (u == 0) { float mm = s1 / 768.f; xm[b] = mm; xrs[b] = rsqrtf(s2 / 768.f - mm * mm + EPSV); }
    __syncthreads();
    float acc[3][8] = {};
    const float* wp[3];
    #pragma unroll
    for (int cc = 0; cc < 3; ++cc) {
      int c = cg * 3 + cc; int g = c >> 3, jj = c & 7;
      wp[cc] = P.WiT + ((size_t)g * 1024 + lj8 + jj) * 1536;
    }
    int idv[8];
    #pragma unroll
    for (int bb = 0; bb < 8; ++bb) idv[bb] = idsh[bb];
    #pragma unroll
    for (int i = 0; i < 6; ++i) {
      int k = i * 128 + ks * 4;
      float4 w0 = *(const float4*)&wp[0][k];
      float4 w1 = *(const float4*)&wp[1][k];
      float4 w2 = *(const float4*)&wp[2][k];
      float4 gam = *(const float4*)&P.lng[k];
      float4 bet = *(const float4*)&P.lnb[k];
      #pragma unroll
      for (int bb = 0; bb < 8; ++bb) {
        float4 xv = *(const float4*)&P.emb[(size_t)idv[bb] * 768 + k];
        float4 xn;
        xn.x = (xv.x - xm[bb]) * xrs[bb] * gam.x + bet.x;
        xn.y = (xv.y - xm[bb]) * xrs[bb] * gam.y + bet.y;
        xn.z = (xv.z - xm[bb]) * xrs[bb] * gam.z + bet.z;
        xn.w = (xv.w - xm[bb]) * xrs[bb] * gam.w + bet.w;
        acc[0][bb] += w0.x*xn.x + w0.y*xn.y + w0.z*xn.z + w0.w*xn.w;
        acc[1][bb] += w1.x*xn.x + w1.y*xn.y + w1.z*xn.z + w1.w*xn.w;
        acc[2][bb] += w2.x*xn.x + w2.y*xn.y + w2.z*xn.z + w2.w*xn.w;
      }
    }
    #pragma unroll
    for (int cc = 0; cc < 3; ++cc)
      #pragma unroll
      for (int bb = 0; bb < 8; ++bb) {
        float v = acc[cc][bb];
        #pragma unroll
        for (int m = 1; m < 32; m <<= 1) v += __shfl_xor(v, m, 64);
        acc[cc][bb] = v;
      }
    if ((tid & 31) == 0) {
      int cgl = tid >> 5;
      #pragma unroll
      for (int cc = 0; cc < 3; ++cc)
        #pragma unroll
        for (int bb = 0; bb < 8; ++bb)
          XW[(cgl * 3 + cc) * 8 + bb] = acc[cc][bb];
    }
    __syncthreads();
  };

  // =================== prologue: weight transposes ===================
  #pragma unroll 1
  for (int g = 0; g < 3; ++g)
    for (int it = 0; it < 6; ++it) {   // low_Wi [3][1536][1024] -> WiT[g][j][k]
      int k = it * 256 + tid;
      const float* src = P.lWi + ((size_t)g * 1536 + k) * 1024 + lj8;
      float4 v0 = *(const float4*)src; float4 v1 = *(const float4*)(src + 4);
      float vv[8] = {v0.x, v0.y, v0.z, v0.w, v1.x, v1.y, v1.z, v1.w};
      for (int jj = 0; jj < 8; ++jj)
        P.WiT[((size_t)g * 1024 + lj8 + jj) * 1536 + k] = vv[jj];
    }
  #pragma unroll 1
  for (int g = 0; g < 3; ++g)
    for (int it = 0; it < 4; ++it) {   // high_Wi [3][1024][768] -> hWiT[g][j][k]
      int k = it * 256 + tid;
      const float* src = P.hWi + ((size_t)g * 1024 + k) * 768 + lj6;
      float2 a = *(const float2*)src, b2v = *(const float2*)(src + 2), c2v = *(const float2*)(src + 4);
      float vv[6] = {a.x, a.y, b2v.x, b2v.y, c2v.x, c2v.y};
      for (int jj = 0; jj < 6; ++jj)
        P.hWiT[((size_t)g * 768 + lj6 + jj) * 1024 + k] = vv[jj];
    }
  #pragma unroll 1
  for (int g = 0; g < 3; ++g)
    for (int it = 0; it < 3; ++it) {   // high_Wh [3][768][768] -> hWhT[g][j][k]
      int k = it * 256 + tid;
      const float* src = P.hWh + ((size_t)g * 768 + k) * 768 + lj6;
      float2 a = *(const float2*)src, b2v = *(const float2*)(src + 2), c2v = *(const float2*)(src + 4);
      float vv[6] = {a.x, a.y, b2v.x, b2v.y, c2v.x, c2v.y};
      for (int jj = 0; jj < 6; ++jj)
        P.hWhT[((size_t)g * 768 + lj6 + jj) * 768 + k] = vv[jj];
    }
  #pragma unroll 1
  for (int g = 0; g < 3; ++g)
    for (int it = 0; it < 4; ++it) {   // low_Wh slice -> LDS
      int k = it * 256 + tid;
      const float* src = P.lWh + ((size_t)g * 1024 + k) * 1024 + lj8;
      float4 v0 = *(const float4*)src; float4 v1 = *(const float4*)(src + 4);
      float vv[8] = {v0.x, v0.y, v0.z, v0.w, v1.x, v1.y, v1.z, v1.w};
      for (int jj = 0; jj < 8; ++jj) WhS[(g * 8 + jj) * 1024 + k] = vv[jj];
    }
  __syncthreads();
  xfun(0);
  arrive(1);
  bool alive = wwait(1);

  // =================== main recurrence ===================
  int rr = 0;
  #pragma unroll 1
  for (int t = 0; alive && t < 256; ++t) {
    #pragma unroll 1
    for (int nn = 0; nn < 3 && alive; ++nn) {
      // ---- round A: xi (XW + hh@Wi_h) + inner iteration 1 ----
      ++rr; int par = rr & 1;
      {
        stage_hh(); __syncthreads();
        float accX[3][8] = {};
        gemm_xih(accX);
        redstage(accX, 0, P.lbi, 1024, 8, lj8, true);
        __syncthreads();
        stage_hl(); __syncthreads();
        float accH[3][8] = {};
        gemm_lowh(accH);
        redstage(accH, 1, P.lbh, 1024, 8, lj8, false);
        __syncthreads();
        stats_put(par, 0, 8); stats_put(par, 1, 8);
        arrive(2 * rr);
        alive = wwait(2 * rr); if (!alive) break;
        sred_read(par, 0, 48);
        gate_low(true);
        arrive(2 * rr + 1);
        alive = wwait(2 * rr + 1); if (!alive) break;
      }
      // ---- inner iterations 2..5 ----
      #pragma unroll 1
      for (int it = 1; it < 5 && alive; ++it) {
        ++rr; par = rr & 1;
        stage_hl(); __syncthreads();
        float acc2[3][8] = {};
        gemm_lowh(acc2);
        redstage(acc2, 1, P.lbh, 1024, 8, lj8, false);
        __syncthreads();
        stats_put(par, 1, 8);
        arrive(2 * rr);
        alive = wwait(2 * rr); if (!alive) break;
        sred_read(par, 24, 24);
        gate_low(false);
        arrive(2 * rr + 1);
        alive = wwait(2 * rr + 1); if (!alive) break;
      }
      if (!alive) break;
      // ---- high GRU round ----
      ++rr; par = rr & 1;
      {
        stage_hl(); __syncthreads();
        float aX[3][8] = {};
        gemm_hxi(aX);
        redstage(aX, 0, P.hbi, 768, 6, lj6, false);
        __syncthreads();
        stage_hh(); __syncthreads();
        float aH[3][8] = {};
        gemm_hhh(aH);
        redstage(aH, 1, P.hbh, 768, 6, lj6, false);
        __syncthreads();
        stats_put(par, 0, 6); stats_put(par, 1, 6);
        arrive(2 * rr);
        alive = wwait(2 * rr); if (!alive) break;
        sred_read(par, 0, 48);
        gate_high(t, nn);
        if (nn == 2 && t < 255) { __syncthreads(); xfun(t + 1); }
        arrive(2 * rr + 1);
        alive = wwait(2 * rr + 1); if (!alive) break;
      }
    }
  }
}

// =================== Wout transpose + bf16 convert ===================
__global__ void __launch_bounds__(256) wout_t(const float* __restrict__ W,
                                              __hip_bfloat16* __restrict__ WT) {
  __shared__ float T[64][65];
  int n0 = blockIdx.x * 64, k0 = blockIdx.y * 64;
  int tid = threadIdx.x;
  int lane16 = tid & 15, grp = tid >> 4;
  #pragma unroll
  for (int i = 0; i < 4; ++i) {
    int kl = i * 16 + grp; int nl = lane16 * 4;
    float4 v = *(const float4*)&W[(size_t)(k0 + kl) * 32000 + n0 + nl];
    T[kl][nl] = v.x; T[kl][nl + 1] = v.y; T[kl][nl + 2] = v.z; T[kl][nl + 3] = v.w;
  }
  __syncthreads();
  #pragma unroll
  for (int i = 0; i < 4; ++i) {
    int nl = i * 16 + grp; int kl = lane16 * 4;
    union { ushort4 v; __hip_bfloat16 h[4]; } u;
    for (int q = 0; q < 4; ++q) u.h[q] = __float2bfloat16(T[kl + q][nl]);
    *(ushort4*)&WT[(size_t)(n0 + nl) * 768 + k0 + kl] = u.v;
  }
}

// =================== logits GEMM: [2048,768] x [768,32000]^T-stored ===================
__global__ void __launch_bounds__(256) logits_gemm(const __hip_bfloat16* __restrict__ Ah,
                                                   const __hip_bfloat16* __restrict__ Bt,
                                                   const float* __restrict__ bias,
                                                   float* __restrict__ out) {
  __shared__ short As[128 * 64];
  __shared__ short Bs[128 * 64];
  int m0 = blockIdx.y * 128, n0 = blockIdx.x * 128;
  int tid = threadIdx.x, lane = tid & 63, w = tid >> 6;
  int wr = w >> 1, wc = w & 1;
  int r16 = lane & 15, khalf = (lane >> 4) * 8;
  f32x4 acc[4][4];
  #pragma unroll
  for (int i = 0; i < 4; ++i)
    #pragma unroll
    for (int j = 0; j < 4; ++j)
      #pragma unroll
      for (int q = 0; q < 4; ++q) acc[i][j][q] = 0.f;

  for (int kt = 0; kt < 12; ++kt) {
    int k0 = kt * 64;
    __syncthreads();
    #pragma unroll
    for (int it = 0; it < 4; ++it) {
      int f = it * 2048 + tid * 8; int row = f >> 6, col = f & 63;
      *(uint4*)&As[f] = *(const uint4*)&Ah[(size_t)(m0 + row) * 768 + k0 + col];
      *(uint4*)&Bs[f] = *(const uint4*)&Bt[(size_t)(n0 + row) * 768 + k0 + col];
    }
    __syncthreads();
    #pragma unroll
    for (int kk = 0; kk < 64; kk += 32) {
      short8 af[4], bfr[4];
      #pragma unroll
      for (int i = 0; i < 4; ++i)
        af[i] = *(short8*)&As[(wr * 64 + i * 16 + r16) * 64 + kk + khalf];
      #pragma unroll
      for (int j = 0; j < 4; ++j)
        bfr[j] = *(short8*)&Bs[(wc * 64 + j * 16 + r16) * 64 + kk + khalf];
      #pragma unroll
      for (int i = 0; i < 4; ++i)
        #pragma unroll
        for (int j = 0; j < 4; ++j)
          acc[i][j] = __builtin_amdgcn_mfma_f32_16x16x32_bf16(af[i], bfr[j], acc[i][j], 0, 0, 0);
    }
  }
  #pragma unroll
  for (int i = 0; i < 4; ++i)
    #pragma unroll
    for (int j = 0; j < 4; ++j)
      #pragma unroll
      for (int q = 0; q < 4; ++q) {
        int m = m0 + wr * 64 + i * 16 + ((lane >> 4) * 4 + q);
        int n = n0 + wc * 64 + j * 16 + (lane & 15);
        out[(size_t)(m & 7) * 8192000 + (size_t)(m >> 3) * 32000 + n] =
            acc[i][j][q] + bias[n];
      }
}

extern "C" void kernel_launch(void* const* d_in, const int* in_sizes, int n_in,
                              void* d_out, int out_size, void* d_ws, size_t ws_size,
                              hipStream_t stream) {
  (void)in_sizes; (void)n_in; (void)out_size; (void)ws_size;
  char* wsb = (char*)d_ws;
  size_t off = 0;
  auto take = [&](size_t bytes) -> void* {
    void* p = wsb + off;
    off += (bytes + 1023) & ~(size_t)1023;
    return p;
  };
  int* arr      = (int*)take((size_t)128 * 4);            // worker epoch slots
  int* rel      = (int*)take((size_t)8 * 16 * 4);         // release lines (sharded)
  float* hlR    = (float*)take((size_t)4 * 8 * 1024 * 4); // h_l x4 replicas
  float* hhR    = (float*)take((size_t)4 * 8 * 768 * 4);  // h_h x4 replicas
  size_t state_bytes = off;                               // ~230 KB -> memset
  u64* statsG   = (u64*)take((size_t)2 * 128 * 48 * 8);   // private stats partials
  u64* sredG    = (u64*)take((size_t)2 * 48 * 8);         // master-reduced (m, rs)
  __hip_bfloat16* hist = (__hip_bfloat16*)take((size_t)2048 * 768 * 2);
  float* WiT    = (float*)take((size_t)3 * 1024 * 1536 * 4);
  float* hWiT   = (float*)take((size_t)3 * 768 * 1024 * 4);
  float* hWhT   = (float*)take((size_t)3 * 768 * 768 * 4);
  __hip_bfloat16* WoutT = (__hip_bfloat16*)take((size_t)32000 * 768 * 2);

  hipMemsetAsync(d_ws, 0, state_bytes, stream);  // arr/rel/hlR/hhR = 0

  wout_t<<<dim3(500, 12), 256, 0, stream>>>((const float*)d_in[20], WoutT);

  PArgs A;
  A.ids = (const int*)d_in[0];   A.emb = (const float*)d_in[1];
  A.lng = (const float*)d_in[2]; A.lnb = (const float*)d_in[3];
  A.lWi = (const float*)d_in[4]; A.lbi = (const float*)d_in[5];
  A.lWh = (const float*)d_in[6]; A.lbh = (const float*)d_in[7];
  A.llig = (const float*)d_in[8];  A.llib = (const float*)d_in[9];
  A.llhg = (const float*)d_in[10]; A.llhb = (const float*)d_in[11];
  A.hWi = (const float*)d_in[12];  A.hbi = (const float*)d_in[13];
  A.hWh = (const float*)d_in[14];  A.hbh = (const float*)d_in[15];
  A.hlig = (const float*)d_in[16]; A.hlib = (const float*)d_in[17];
  A.hlhg = (const float*)d_in[18]; A.hlhb = (const float*)d_in[19];
  A.arr = arr; A.rel = rel; A.statsG = statsG; A.sredG = sredG;
  A.hlR = hlR; A.hhR = hhR;
  A.hist = hist; A.WiT = WiT; A.hWiT = hWiT; A.hWhT = hWhT;

  hrm_recur<<<NWG + 1, NTH, 0, stream>>>(A);

  logits_gemm<<<dim3(250, 16), 256, 0, stream>>>(hist, WoutT,
                                                 (const float*)d_in[21],
                                                 (float*)d_out);
}